// Round 1
// baseline (9274.948 us; speedup 1.0000x reference)
//
#include <hip/hip_runtime.h>
#include <math.h>

// Problem constants
#define BB 8
#define SS 2048
#define DM 512
#define DK 64
#define DFF 2048
#define ROWS (BB*SS)          // 16384
#define NTOT (ROWS*DM)        // 8388608
#define LN_EPS 1e-5
#define PAD_IDX 0

// ---------------------------------------------------------------------------
// Embedding + positional encoding:  x[b,s,d] = emb[ids[b,s]][d]*mask + pe(s,d)
// pe(s,d) = (d even ? sin : cos)(s / 10000^(2d/512))
// ---------------------------------------------------------------------------
__global__ __launch_bounds__(256) void embed_kernel(const int* __restrict__ ids,
                                                    const float* __restrict__ emb,
                                                    float* __restrict__ x) {
    int idx = blockIdx.x * 256 + threadIdx.x;
    if (idx >= NTOT) return;
    int d   = idx & (DM - 1);
    int row = idx >> 9;             // b*2048 + s
    int s   = row & (SS - 1);
    int id  = ids[row];
    float e = (id != PAD_IDX) ? emb[(size_t)id * DM + d] : 0.0f;
    float ex  = 2.0f * (float)d / 512.0f;
    float div = powf(10000.0f, ex);
    float arg = (float)s / div;
    float pe  = (d & 1) ? cosf(arg) : sinf(arg);
    x[idx] = e + pe;
}

// ---------------------------------------------------------------------------
// Pack Wq|Wk|Wv -> Wqkv [512][192], biases -> bqkv[192]
// ---------------------------------------------------------------------------
__global__ __launch_bounds__(256) void packqkv_kernel(const float* __restrict__ Wq,
                                                      const float* __restrict__ Wk,
                                                      const float* __restrict__ Wv,
                                                      const float* __restrict__ bq,
                                                      const float* __restrict__ bk,
                                                      const float* __restrict__ bv,
                                                      float* __restrict__ Wqkv,
                                                      float* __restrict__ bqkv) {
    int i = blockIdx.x * 256 + threadIdx.x;
    if (i < 512 * 192) {
        int d = i / 192, c = i % 192;
        float v = (c < 64) ? Wq[d * 64 + c]
                : (c < 128) ? Wk[d * 64 + (c - 64)]
                            : Wv[d * 64 + (c - 128)];
        Wqkv[i] = v;
    }
    if (i < 192) {
        bqkv[i] = (i < 64) ? bq[i] : (i < 128) ? bk[i - 64] : bv[i - 128];
    }
}

// Wo_sum[k][e] = sum_h Wo[h*64+k][e]   (head tiling collapse)
__global__ __launch_bounds__(256) void wosum_kernel(const float* __restrict__ Wo,
                                                    float* __restrict__ WoS) {
    int i = blockIdx.x * 256 + threadIdx.x;
    if (i >= 64 * 512) return;
    int k = i >> 9, e = i & 511;
    float s = 0.f;
#pragma unroll
    for (int h = 0; h < 8; ++h) s += Wo[(size_t)(h * 64 + k) * 512 + e];
    WoS[i] = s;
}

// ---------------------------------------------------------------------------
// Generic fp32 tiled GEMM: C[M,N] = A[M,K]@B[K,N] + bias (+resid) (+relu)
// 64x64 tile, 256 threads, 4x4 per thread, K-chunk 16. All dims multiples.
// ---------------------------------------------------------------------------
template <bool RELU, bool RESID>
__global__ __launch_bounds__(256) void gemm64(const float* __restrict__ A,
                                              const float* __restrict__ B,
                                              const float* __restrict__ bias,
                                              const float* __restrict__ resid,
                                              float* __restrict__ C,
                                              int M, int N, int K) {
    __shared__ float As[16][68];   // k-major, padded
    __shared__ float Bs[16][68];
    const int t  = threadIdx.x;
    const int m0 = blockIdx.y * 64;
    const int n0 = blockIdx.x * 64;
    const int tm = t >> 4, tn = t & 15;
    float acc[4][4] = {};

    for (int k0 = 0; k0 < K; k0 += 16) {
#pragma unroll
        for (int i = 0; i < 4; ++i) {        // A tile 64x16 -> As[k][m]
            int e = t + i * 256;
            int row = e >> 4, col = e & 15;
            As[col][row] = A[(size_t)(m0 + row) * K + k0 + col];
        }
#pragma unroll
        for (int i = 0; i < 4; ++i) {        // B tile 16x64 -> Bs[k][n]
            int e = t + i * 256;
            int row = e >> 6, col = e & 63;
            Bs[row][col] = B[(size_t)(k0 + row) * N + n0 + col];
        }
        __syncthreads();
#pragma unroll
        for (int kk = 0; kk < 16; ++kk) {
            float4 a4 = *(const float4*)&As[kk][tm * 4];
            float4 b4 = *(const float4*)&Bs[kk][tn * 4];
            float a[4] = {a4.x, a4.y, a4.z, a4.w};
            float b[4] = {b4.x, b4.y, b4.z, b4.w};
#pragma unroll
            for (int i = 0; i < 4; ++i)
#pragma unroll
                for (int j = 0; j < 4; ++j)
                    acc[i][j] = fmaf(a[i], b[j], acc[i][j]);
        }
        __syncthreads();
    }
#pragma unroll
    for (int i = 0; i < 4; ++i) {
        int m = m0 + tm * 4 + i;
#pragma unroll
        for (int j = 0; j < 4; ++j) {
            int n = n0 + tn * 4 + j;
            float v = acc[i][j] + bias[n];
            if (RESID) v += resid[(size_t)m * N + n];
            if (RELU)  v = fmaxf(v, 0.0f);
            C[(size_t)m * N + n] = v;
        }
    }
}

// ---------------------------------------------------------------------------
// Flash attention (no mask, full softmax), one head, scores/32.
// Block: 64 q-rows x full key loop in 64-key tiles. 256 thr = 64 rows x 4.
// qkv: [16384][192] (q|k|v), head out: [16384][64]
// ---------------------------------------------------------------------------
__global__ __launch_bounds__(256) void attn_kernel(const float* __restrict__ qkv,
                                                   float* __restrict__ head) {
    const int b  = blockIdx.y;
    const int q0 = blockIdx.x * 64;
    const int t  = threadIdx.x;
    const int r  = t >> 2;      // q-row in tile
    const int c  = t & 3;       // column group
    __shared__ float Qs[64][68];
    __shared__ float Ks[64][68];
    __shared__ float Vs[64][68];
    __shared__ float Ps[64][68];

    const float* qbase  = qkv + (size_t)(b * SS + q0) * 192;
    const float* kvbase = qkv + (size_t)(b * SS) * 192;
#pragma unroll
    for (int i = 0; i < 16; ++i) {
        int e = t + i * 256;
        int row = e >> 6, d = e & 63;
        Qs[row][d] = qbase[(size_t)row * 192 + d];
    }
    __syncthreads();

    float m_i = -3.0e38f, l_i = 0.f;
    float acc[16];
#pragma unroll
    for (int i = 0; i < 16; ++i) acc[i] = 0.f;

    for (int kt = 0; kt < SS / 64; ++kt) {
#pragma unroll
        for (int i = 0; i < 16; ++i) {
            int e = t + i * 256;
            int row = e >> 6, d = e & 63;
            const float* src = kvbase + (size_t)(kt * 64 + row) * 192;
            Ks[row][d] = src[64 + d];
            Vs[row][d] = src[128 + d];
        }
        __syncthreads();

        // scores for keys j = c*16 .. c*16+15 of row r
        float s[16];
#pragma unroll
        for (int jj = 0; jj < 16; ++jj) s[jj] = 0.f;
        for (int d4 = 0; d4 < 16; ++d4) {
            float4 q4 = *(const float4*)&Qs[r][d4 * 4];
#pragma unroll
            for (int jj = 0; jj < 16; ++jj) {
                float4 k4 = *(const float4*)&Ks[c * 16 + jj][d4 * 4];
                s[jj] = fmaf(q4.x, k4.x, s[jj]);
                s[jj] = fmaf(q4.y, k4.y, s[jj]);
                s[jj] = fmaf(q4.z, k4.z, s[jj]);
                s[jj] = fmaf(q4.w, k4.w, s[jj]);
            }
        }
        float mloc = -3.0e38f;
#pragma unroll
        for (int jj = 0; jj < 16; ++jj) {
            s[jj] *= (1.0f / 32.0f);                 // SCORE_DIV = 32.0
            mloc = fmaxf(mloc, s[jj]);
        }
        mloc = fmaxf(mloc, __shfl_xor(mloc, 1));
        mloc = fmaxf(mloc, __shfl_xor(mloc, 2));
        float m_new = fmaxf(m_i, mloc);
        float alpha = __expf(m_i - m_new);
        float psum = 0.f;
#pragma unroll
        for (int jj = 0; jj < 16; ++jj) {
            s[jj] = __expf(s[jj] - m_new);
            psum += s[jj];
        }
        psum += __shfl_xor(psum, 1);
        psum += __shfl_xor(psum, 2);
        l_i = l_i * alpha + psum;
        m_i = m_new;
#pragma unroll
        for (int i = 0; i < 16; ++i) acc[i] *= alpha;
#pragma unroll
        for (int jj = 0; jj < 16; ++jj) Ps[r][c * 16 + jj] = s[jj];
        __syncthreads();
        // acc[d] += sum_j P[r][j] * V[j][d], d = c*16 + i
        for (int j = 0; j < 64; ++j) {
            float p = Ps[r][j];
#pragma unroll
            for (int i = 0; i < 16; ++i)
                acc[i] = fmaf(p, Vs[j][c * 16 + i], acc[i]);
        }
        __syncthreads();
    }
    float inv_l = 1.0f / l_i;
    float* out = head + (size_t)(b * SS + q0 + r) * 64 + c * 16;
#pragma unroll
    for (int i = 0; i < 16; ++i) out[i] = acc[i] * inv_l;
}

// ---------------------------------------------------------------------------
// Whole-tensor LayerNorm: global sum/sumsq (f64 atomics) then normalize.
// ---------------------------------------------------------------------------
__global__ __launch_bounds__(256) void reduce_kernel(const float* __restrict__ x,
                                                     double* __restrict__ red, int n) {
    double s = 0.0, sq = 0.0;
    for (int i = blockIdx.x * blockDim.x + threadIdx.x; i < n;
         i += gridDim.x * blockDim.x) {
        float v = x[i];
        s += (double)v;
        sq += (double)v * (double)v;
    }
    for (int o = 32; o; o >>= 1) {
        s  += __shfl_down(s, o);
        sq += __shfl_down(sq, o);
    }
    __shared__ double ls[4], lsq[4];
    int w = threadIdx.x >> 6, lane = threadIdx.x & 63;
    if (lane == 0) { ls[w] = s; lsq[w] = sq; }
    __syncthreads();
    if (threadIdx.x == 0) {
        double S = ls[0] + ls[1] + ls[2] + ls[3];
        double SQ = lsq[0] + lsq[1] + lsq[2] + lsq[3];
        atomicAdd(&red[0], S);
        atomicAdd(&red[1], SQ);
    }
}

__global__ __launch_bounds__(256) void lnorm_kernel(const float* __restrict__ in,
                                                    float* __restrict__ out,
                                                    const double* __restrict__ red,
                                                    int n) {
    double mean = red[0] / n;
    double var  = red[1] / n - mean * mean;
    float mu   = (float)mean;
    float rstd = (float)(1.0 / sqrt(var + LN_EPS));
    for (int i = blockIdx.x * blockDim.x + threadIdx.x; i < n;
         i += gridDim.x * blockDim.x)
        out[i] = (in[i] - mu) * rstd;
}

// ---------------------------------------------------------------------------
extern "C" void kernel_launch(void* const* d_in, const int* in_sizes, int n_in,
                              void* d_out, int out_size, void* d_ws, size_t ws_size,
                              hipStream_t stream) {
    const int*   ids = (const int*)d_in[0];
    const float* emb = (const float*)d_in[1];
    const float* Wq  = (const float*)d_in[2];
    const float* bq  = (const float*)d_in[3];
    const float* Wk  = (const float*)d_in[4];
    const float* bk  = (const float*)d_in[5];
    const float* Wv  = (const float*)d_in[6];
    const float* bv  = (const float*)d_in[7];
    const float* Wo  = (const float*)d_in[8];
    const float* bo  = (const float*)d_in[9];
    const float* W1  = (const float*)d_in[10];
    const float* b1  = (const float*)d_in[11];
    const float* W2  = (const float*)d_in[12];
    const float* b2  = (const float*)d_in[13];

    float* x  = (float*)d_out;                 // [16384][512], doubles as tmp
    float* ws = (float*)d_ws;
    float* x1   = ws;                          // 8.4M floats
    float* U    = ws + (size_t)NTOT;           // 8.4M floats (qkv/head | hidden chunk)
    float* qkv  = U;                           // [16384][192]
    float* head = U + (size_t)ROWS * 192;      // [16384][64]
    float* hch  = U;                           // [4096][2048] (after head consumed)
    float* Wqkv = ws + (size_t)2 * NTOT;       // [512][192]
    float* bqkv = Wqkv + 512 * 192;            // [192] (pad 256)
    float* WoS  = bqkv + 256;                  // [64][512]
    double* red = (double*)(WoS + 64 * 512);   // 2 doubles

    packqkv_kernel<<<(512 * 192 + 255) / 256, 256, 0, stream>>>(Wq, Wk, Wv, bq, bk, bv, Wqkv, bqkv);
    wosum_kernel<<<(64 * 512 + 255) / 256, 256, 0, stream>>>(Wo, WoS);
    embed_kernel<<<NTOT / 256, 256, 0, stream>>>(ids, emb, x);

    for (int rep = 0; rep < 6; ++rep) {
        // QKV: [16384,512] @ [512,192]
        gemm64<false, false><<<dim3(3, 256), 256, 0, stream>>>(x, Wqkv, bqkv, nullptr, qkv, ROWS, 192, DM);
        // attention -> head [16384,64]
        attn_kernel<<<dim3(SS / 64, BB), 256, 0, stream>>>(qkv, head);
        // mha + x (in place into x): [16384,64] @ [64,512] + bo + resid(x)
        gemm64<false, true><<<dim3(8, 256), 256, 0, stream>>>(head, WoS, bo, x, x, ROWS, DM, DK);
        // LN1: x -> x1
        hipMemsetAsync(red, 0, 16, stream);
        reduce_kernel<<<1024, 256, 0, stream>>>(x, red, NTOT);
        lnorm_kernel<<<4096, 256, 0, stream>>>(x, x1, red, NTOT);
        // FF in 4 row-chunks of 4096; FF2 fuses +x1 residual, writes into x
        for (int cch = 0; cch < 4; ++cch) {
            const float* xa = x1 + (size_t)cch * 4096 * DM;
            float* xo = x + (size_t)cch * 4096 * DM;
            gemm64<true, false><<<dim3(32, 64), 256, 0, stream>>>(xa, W1, b1, nullptr, hch, 4096, DFF, DM);
            gemm64<false, true><<<dim3(8, 64), 256, 0, stream>>>(hch, W2, b2, xa, xo, 4096, DM, DFF);
        }
        // LN2: x -> x (in place)
        hipMemsetAsync(red, 0, 16, stream);
        reduce_kernel<<<1024, 256, 0, stream>>>(x, red, NTOT);
        lnorm_kernel<<<4096, 256, 0, stream>>>(x, x, red, NTOT);
    }
}

// Round 2
// 4035.344 us; speedup vs baseline: 2.2984x; 2.2984x over previous
//
#include <hip/hip_runtime.h>
#include <math.h>

// Problem constants
#define BB 8
#define SS 2048
#define DM 512
#define DK 64
#define DFF 2048
#define ROWS (BB*SS)          // 16384
#define NTOT (ROWS*DM)        // 8388608
#define LN_EPS 1e-5
#define PAD_IDX 0

typedef __attribute__((ext_vector_type(8))) short short8;
typedef __attribute__((ext_vector_type(4))) float f32x4;

__device__ __forceinline__ short f2b(float f) {        // fp32 -> bf16 (RNE)
    unsigned u = __float_as_uint(f);
    unsigned r = (u + 0x7fffu + ((u >> 16) & 1u)) >> 16;
    return (short)r;
}
__device__ __forceinline__ float b2f(short s) {        // bf16 -> fp32
    return __uint_as_float(((unsigned)(unsigned short)s) << 16);
}

__device__ __forceinline__ void async16(const void* g, void* l) {
    __builtin_amdgcn_global_load_lds(
        (const __attribute__((address_space(1))) void*)g,
        (__attribute__((address_space(3))) void*)l, 16, 0, 0);
}

// ---------------------------------------------------------------------------
// Embedding + positional encoding -> x fp32 AND xb bf16
// ---------------------------------------------------------------------------
__global__ __launch_bounds__(256) void embed_kernel(const int* __restrict__ ids,
                                                    const float* __restrict__ emb,
                                                    float* __restrict__ x,
                                                    short* __restrict__ xb) {
    int idx = blockIdx.x * 256 + threadIdx.x;
    if (idx >= NTOT) return;
    int d   = idx & (DM - 1);
    int row = idx >> 9;
    int s   = row & (SS - 1);
    int id  = ids[row];
    float e = (id != PAD_IDX) ? emb[(size_t)id * DM + d] : 0.0f;
    float ex  = 2.0f * (float)d / 512.0f;
    float div = powf(10000.0f, ex);
    float arg = (float)s / div;
    float pe  = (d & 1) ? cosf(arg) : sinf(arg);
    float v = e + pe;
    x[idx]  = v;
    xb[idx] = f2b(v);
}

// ---------------------------------------------------------------------------
// Weight packing: WqkvT bf16 [256][512] (rows 192..255 zero) + bqkv fp32[256]
// ---------------------------------------------------------------------------
__global__ __launch_bounds__(256) void packqkvT_kernel(const float* __restrict__ Wq,
                                                       const float* __restrict__ Wk,
                                                       const float* __restrict__ Wv,
                                                       const float* __restrict__ bq,
                                                       const float* __restrict__ bk,
                                                       const float* __restrict__ bv,
                                                       short* __restrict__ WqkvT,
                                                       float* __restrict__ bqkv) {
    int i = blockIdx.x * 256 + threadIdx.x;
    if (i < 256 * 512) {
        int n = i >> 9, k = i & 511;
        float v = (n < 64)  ? Wq[k * 64 + n]
                : (n < 128) ? Wk[k * 64 + (n - 64)]
                : (n < 192) ? Wv[k * 64 + (n - 128)] : 0.0f;
        WqkvT[i] = f2b(v);
    }
    if (i < 256)
        bqkv[i] = (i < 64) ? bq[i] : (i < 128) ? bk[i - 64] : (i < 192) ? bv[i - 128] : 0.0f;
}

// WoST bf16 [512][64]: WoST[e][k] = sum_h Wo[h*64+k][e]
__global__ __launch_bounds__(256) void wosumT_kernel(const float* __restrict__ Wo,
                                                     short* __restrict__ WoST) {
    int i = blockIdx.x * 256 + threadIdx.x;
    if (i >= 512 * 64) return;
    int e = i >> 6, k = i & 63;
    float s = 0.f;
#pragma unroll
    for (int h = 0; h < 8; ++h) s += Wo[(size_t)(h * 64 + k) * 512 + e];
    WoST[i] = f2b(s);
}

// Tiled transpose fp32[R][C] -> bf16[C][R]
__global__ __launch_bounds__(256) void transpose_b16(const float* __restrict__ in,
                                                     short* __restrict__ out,
                                                     int R, int C) {
    __shared__ float tile[32][33];
    int bx = blockIdx.x * 32;   // C offset
    int by = blockIdx.y * 32;   // R offset
    int tx = threadIdx.x & 31, ty = threadIdx.x >> 5;
#pragma unroll
    for (int i = 0; i < 32; i += 8)
        tile[ty + i][tx] = in[(size_t)(by + ty + i) * C + bx + tx];
    __syncthreads();
#pragma unroll
    for (int i = 0; i < 32; i += 8)
        out[(size_t)(bx + ty + i) * R + by + tx] = f2b(tile[tx][ty + i]);
}

// ---------------------------------------------------------------------------
// bf16 MFMA GEMM, 128x128 tile, BK=32, 256 thr = 4 waves (2x2), 4x4 frags.
// A bf16 [M][K] row-major; BT bf16 [N][K] row-major; bias fp32 [N].
// RESID: 0 none, 1 fp32, 2 bf16.  OUTBF: write bf16 else fp32.
// ---------------------------------------------------------------------------
template <bool RELU, int RESID, bool OUTBF>
__global__ __launch_bounds__(256) void gemm_mfma(const short* __restrict__ A,
                                                 const short* __restrict__ BT,
                                                 const float* __restrict__ bias,
                                                 const void* __restrict__ resid,
                                                 void* __restrict__ C,
                                                 int M, int N, int K) {
    __shared__ short As[128 * 32];
    __shared__ short Bs[128 * 32];
    const int t   = threadIdx.x;
    const int wv  = t >> 6;
    const int l   = t & 63;
    const int wr  = wv >> 1, wc = wv & 1;
    const int q   = l >> 4,  l16 = l & 15;
    const long m0 = (long)blockIdx.y * 128;
    const long n0 = (long)blockIdx.x * 128;

    f32x4 acc[4][4] = {};

    const int srow = wv * 16 + (l >> 2);   // staging row within 128-tile (issue 0)
    const int kcol = (l & 3) * 8;          // staging k-element offset

    for (int k0 = 0; k0 < K; k0 += 32) {
#pragma unroll
        for (int i = 0; i < 2; ++i) {
            const short* ga = A  + (m0 + srow + i * 64) * (long)K + k0 + kcol;
            const short* gb = BT + (n0 + srow + i * 64) * (long)K + k0 + kcol;
            async16(ga, &As[(wv * 16 + i * 64) * 32 + l * 8]);
            async16(gb, &Bs[(wv * 16 + i * 64) * 32 + l * 8]);
        }
        __syncthreads();   // drains vmcnt (global_load_lds) + protects reads
        short8 af[4], bfr[4];
#pragma unroll
        for (int i = 0; i < 4; ++i) {
            af[i]  = *(const short8*)&As[(wr * 64 + i * 16 + l16) * 32 + q * 8];
            bfr[i] = *(const short8*)&Bs[(wc * 64 + i * 16 + l16) * 32 + q * 8];
        }
#pragma unroll
        for (int mt = 0; mt < 4; ++mt)
#pragma unroll
            for (int nt = 0; nt < 4; ++nt)
                acc[mt][nt] = __builtin_amdgcn_mfma_f32_16x16x32_bf16(
                    af[mt], bfr[nt], acc[mt][nt], 0, 0, 0);
        __syncthreads();   // protect LDS from next iteration's staging
    }
#pragma unroll
    for (int mt = 0; mt < 4; ++mt) {
        const long rowb = m0 + wr * 64 + mt * 16 + q * 4;
#pragma unroll
        for (int nt = 0; nt < 4; ++nt) {
            const long col = n0 + wc * 64 + nt * 16 + l16;
            const float bv = bias[col];
#pragma unroll
            for (int r = 0; r < 4; ++r) {
                const long idx = (rowb + r) * (long)N + col;
                float v = acc[mt][nt][r] + bv;
                if (RESID == 1) v += ((const float*)resid)[idx];
                if (RESID == 2) v += b2f(((const short*)resid)[idx]);
                if (RELU) v = fmaxf(v, 0.0f);
                if (OUTBF) ((short*)C)[idx] = f2b(v);
                else       ((float*)C)[idx] = v;
            }
        }
    }
}

// ---------------------------------------------------------------------------
// Flash attention fp32 (unchanged math), qkv stride 256, head out bf16.
// ---------------------------------------------------------------------------
__global__ __launch_bounds__(256) void attn_kernel(const float* __restrict__ qkv,
                                                   short* __restrict__ head) {
    const int b  = blockIdx.y;
    const int q0 = blockIdx.x * 64;
    const int t  = threadIdx.x;
    const int r  = t >> 2;
    const int c  = t & 3;
    __shared__ float Qs[64][68];
    __shared__ float Ks[64][68];
    __shared__ float Vs[64][68];
    __shared__ float Ps[64][68];

    const float* qbase  = qkv + (size_t)(b * SS + q0) * 256;
    const float* kvbase = qkv + (size_t)(b * SS) * 256;
#pragma unroll
    for (int i = 0; i < 16; ++i) {
        int e = t + i * 256;
        int row = e >> 6, d = e & 63;
        Qs[row][d] = qbase[(size_t)row * 256 + d];
    }
    __syncthreads();

    float m_i = -3.0e38f, l_i = 0.f;
    float acc[16];
#pragma unroll
    for (int i = 0; i < 16; ++i) acc[i] = 0.f;

    for (int kt = 0; kt < SS / 64; ++kt) {
#pragma unroll
        for (int i = 0; i < 16; ++i) {
            int e = t + i * 256;
            int row = e >> 6, d = e & 63;
            const float* src = kvbase + (size_t)(kt * 64 + row) * 256;
            Ks[row][d] = src[64 + d];
            Vs[row][d] = src[128 + d];
        }
        __syncthreads();

        float s[16];
#pragma unroll
        for (int jj = 0; jj < 16; ++jj) s[jj] = 0.f;
        for (int d4 = 0; d4 < 16; ++d4) {
            float4 q4 = *(const float4*)&Qs[r][d4 * 4];
#pragma unroll
            for (int jj = 0; jj < 16; ++jj) {
                float4 k4 = *(const float4*)&Ks[c * 16 + jj][d4 * 4];
                s[jj] = fmaf(q4.x, k4.x, s[jj]);
                s[jj] = fmaf(q4.y, k4.y, s[jj]);
                s[jj] = fmaf(q4.z, k4.z, s[jj]);
                s[jj] = fmaf(q4.w, k4.w, s[jj]);
            }
        }
        float mloc = -3.0e38f;
#pragma unroll
        for (int jj = 0; jj < 16; ++jj) {
            s[jj] *= (1.0f / 32.0f);
            mloc = fmaxf(mloc, s[jj]);
        }
        mloc = fmaxf(mloc, __shfl_xor(mloc, 1));
        mloc = fmaxf(mloc, __shfl_xor(mloc, 2));
        float m_new = fmaxf(m_i, mloc);
        float alpha = __expf(m_i - m_new);
        float psum = 0.f;
#pragma unroll
        for (int jj = 0; jj < 16; ++jj) {
            s[jj] = __expf(s[jj] - m_new);
            psum += s[jj];
        }
        psum += __shfl_xor(psum, 1);
        psum += __shfl_xor(psum, 2);
        l_i = l_i * alpha + psum;
        m_i = m_new;
#pragma unroll
        for (int i = 0; i < 16; ++i) acc[i] *= alpha;
#pragma unroll
        for (int jj = 0; jj < 16; ++jj) Ps[r][c * 16 + jj] = s[jj];
        __syncthreads();
        for (int j = 0; j < 64; ++j) {
            float p = Ps[r][j];
#pragma unroll
            for (int i = 0; i < 16; ++i)
                acc[i] = fmaf(p, Vs[j][c * 16 + i], acc[i]);
        }
        __syncthreads();
    }
    float inv_l = 1.0f / l_i;
    short* out = head + (size_t)(b * SS + q0 + r) * 64 + c * 16;
#pragma unroll
    for (int i = 0; i < 16; ++i) out[i] = f2b(acc[i] * inv_l);
}

// ---------------------------------------------------------------------------
// Whole-tensor LayerNorm
// ---------------------------------------------------------------------------
__global__ __launch_bounds__(256) void reduce_kernel(const float* __restrict__ x,
                                                     double* __restrict__ red, int n) {
    double s = 0.0, sq = 0.0;
    for (int i = blockIdx.x * blockDim.x + threadIdx.x; i < n;
         i += gridDim.x * blockDim.x) {
        float v = x[i];
        s += (double)v;
        sq += (double)v * (double)v;
    }
    for (int o = 32; o; o >>= 1) {
        s  += __shfl_down(s, o);
        sq += __shfl_down(sq, o);
    }
    __shared__ double ls[4], lsq[4];
    int w = threadIdx.x >> 6, lane = threadIdx.x & 63;
    if (lane == 0) { ls[w] = s; lsq[w] = sq; }
    __syncthreads();
    if (threadIdx.x == 0) {
        atomicAdd(&red[0], ls[0] + ls[1] + ls[2] + ls[3]);
        atomicAdd(&red[1], lsq[0] + lsq[1] + lsq[2] + lsq[3]);
    }
}

// normalize -> optional fp32 out, optional bf16 out
__global__ __launch_bounds__(256) void lnorm2_kernel(const float* __restrict__ in,
                                                     float* __restrict__ out32,
                                                     short* __restrict__ out16,
                                                     const double* __restrict__ red,
                                                     int n) {
    double mean = red[0] / n;
    double var  = red[1] / n - mean * mean;
    float mu   = (float)mean;
    float rstd = (float)(1.0 / sqrt(var + LN_EPS));
    for (int i = blockIdx.x * blockDim.x + threadIdx.x; i < n;
         i += gridDim.x * blockDim.x) {
        float v = (in[i] - mu) * rstd;
        if (out32) out32[i] = v;
        if (out16) out16[i] = f2b(v);
    }
}

// ---------------------------------------------------------------------------
extern "C" void kernel_launch(void* const* d_in, const int* in_sizes, int n_in,
                              void* d_out, int out_size, void* d_ws, size_t ws_size,
                              hipStream_t stream) {
    const int*   ids = (const int*)d_in[0];
    const float* emb = (const float*)d_in[1];
    const float* Wq  = (const float*)d_in[2];
    const float* bq  = (const float*)d_in[3];
    const float* Wk  = (const float*)d_in[4];
    const float* bk  = (const float*)d_in[5];
    const float* Wv  = (const float*)d_in[6];
    const float* bv  = (const float*)d_in[7];
    const float* Wo  = (const float*)d_in[8];
    const float* bo  = (const float*)d_in[9];
    const float* W1  = (const float*)d_in[10];
    const float* b1  = (const float*)d_in[11];
    const float* W2  = (const float*)d_in[12];
    const float* b2  = (const float*)d_in[13];

    float* x = (float*)d_out;                        // [16384][512] fp32

    // Workspace layout (bytes). R1 = [qkv|xb] aliased with FF hidden chunk.
    char* w = (char*)d_ws;
    float*  qkv   = (float*)(w + 0);                 // [16384][256] fp32, 16 MB
    short*  xb    = (short*)(w + 16777216);          // [16384][512] bf16, 16 MB
    short*  hch   = (short*)(w + 0);                 // [8192][2048] bf16, 32 MB (FF phase)
    short*  x1b   = (short*)(w + 33554432);          // [16384][512] bf16, 16 MB
    short*  head  = (short*)(w + 50331648);          // [16384][64]  bf16,  2 MB
    short*  WqkvT = (short*)(w + 52428800);          // [256][512]
    float*  bqkv  = (float*)(w + 52690944);          // [256]
    short*  WoST  = (short*)(w + 52691968);          // [512][64]
    short*  W1T   = (short*)(w + 52757504);          // [2048][512]
    short*  W2T   = (short*)(w + 54854656);          // [512][2048]
    double* red   = (double*)(w + 56951808);         // 2 doubles

    // ---- setup (once per launch) ----
    packqkvT_kernel<<<(256 * 512 + 255) / 256, 256, 0, stream>>>(Wq, Wk, Wv, bq, bk, bv, WqkvT, bqkv);
    wosumT_kernel<<<(512 * 64 + 255) / 256, 256, 0, stream>>>(Wo, WoST);
    transpose_b16<<<dim3(2048 / 32, 512 / 32), 256, 0, stream>>>(W1, W1T, 512, 2048);
    transpose_b16<<<dim3(512 / 32, 2048 / 32), 256, 0, stream>>>(W2, W2T, 2048, 512);
    embed_kernel<<<NTOT / 256, 256, 0, stream>>>(ids, emb, x, xb);

    for (int rep = 0; rep < 6; ++rep) {
        // QKV: xb[16384,512] @ WqkvT -> qkv fp32 [16384,256]
        gemm_mfma<false, 0, false><<<dim3(2, 128), 256, 0, stream>>>(
            xb, WqkvT, bqkv, nullptr, qkv, ROWS, 256, DM);
        // attention -> head bf16 [16384,64]
        attn_kernel<<<dim3(SS / 64, BB), 256, 0, stream>>>(qkv, head);
        // out-proj: head @ WoST + bo + x -> x (fp32, in place)
        gemm_mfma<false, 1, false><<<dim3(4, 128), 256, 0, stream>>>(
            head, WoST, bo, x, x, ROWS, DM, DK);
        // LN1: x -> x1b (bf16)
        hipMemsetAsync(red, 0, 16, stream);
        reduce_kernel<<<1024, 256, 0, stream>>>(x, red, NTOT);
        lnorm2_kernel<<<4096, 256, 0, stream>>>(x, nullptr, x1b, red, NTOT);
        // FF in 2 row-chunks of 8192 (hidden chunk aliases qkv/xb region)
        for (int c = 0; c < 2; ++c) {
            const size_t off = (size_t)c * 8192 * DM;
            gemm_mfma<true, 0, true><<<dim3(16, 64), 256, 0, stream>>>(
                x1b + off, W1T, b1, nullptr, hch, 8192, DFF, DM);
            gemm_mfma<false, 2, false><<<dim3(4, 64), 256, 0, stream>>>(
                hch, W2T, b2, x1b + off, x + off, 8192, DM, DFF);
        }
        // LN2: x -> x (fp32) + xb (bf16, next rep's QKV input)
        hipMemsetAsync(red, 0, 16, stream);
        reduce_kernel<<<1024, 256, 0, stream>>>(x, red, NTOT);
        lnorm2_kernel<<<4096, 256, 0, stream>>>(x, x, xb, red, NTOT);
    }
}

// Round 4
// 2110.576 us; speedup vs baseline: 4.3945x; 1.9120x over previous
//
#include <hip/hip_runtime.h>
#include <math.h>

// Problem constants
#define BB 8
#define SS 2048
#define DM 512
#define DK 64
#define DFF 2048
#define ROWS (BB*SS)          // 16384
#define NTOT (ROWS*DM)        // 8388608
#define LN_EPS 1e-5
#define PAD_IDX 0

typedef __attribute__((ext_vector_type(8))) short short8;
typedef __attribute__((ext_vector_type(4))) short s16x4;
typedef __attribute__((ext_vector_type(4))) float f32x4;

__device__ __forceinline__ short f2b(float f) {        // fp32 -> bf16 (RNE)
    unsigned u = __float_as_uint(f);
    unsigned r = (u + 0x7fffu + ((u >> 16) & 1u)) >> 16;
    return (short)r;
}
__device__ __forceinline__ float b2f(short s) {        // bf16 -> fp32
    return __uint_as_float(((unsigned)(unsigned short)s) << 16);
}

// ---------------------------------------------------------------------------
// Embedding + positional encoding -> x fp32 AND xb bf16; zero LN slots
// ---------------------------------------------------------------------------
__global__ __launch_bounds__(256) void embed_kernel(const int* __restrict__ ids,
                                                    const float* __restrict__ emb,
                                                    float* __restrict__ x,
                                                    short* __restrict__ xb,
                                                    double* __restrict__ red) {
    int idx = blockIdx.x * 256 + threadIdx.x;
    if (idx < 24) red[idx] = 0.0;              // 12 LN slots x (sum,sumsq)
    if (idx >= NTOT) return;
    int d   = idx & (DM - 1);
    int row = idx >> 9;
    int s   = row & (SS - 1);
    int id  = ids[row];
    float e = (id != PAD_IDX) ? emb[(size_t)id * DM + d] : 0.0f;
    float ex  = 2.0f * (float)d / 512.0f;
    float div = powf(10000.0f, ex);
    float arg = (float)s / div;
    float pe  = (d & 1) ? cosf(arg) : sinf(arg);
    float v = e + pe;
    x[idx]  = v;
    xb[idx] = f2b(v);
}

// ---------------------------------------------------------------------------
// Weight packing: WqkvT bf16 [256][512] (rows 192..255 zero) + bqkv fp32[256]
// ---------------------------------------------------------------------------
__global__ __launch_bounds__(256) void packqkvT_kernel(const float* __restrict__ Wq,
                                                       const float* __restrict__ Wk,
                                                       const float* __restrict__ Wv,
                                                       const float* __restrict__ bq,
                                                       const float* __restrict__ bk,
                                                       const float* __restrict__ bv,
                                                       short* __restrict__ WqkvT,
                                                       float* __restrict__ bqkv) {
    int i = blockIdx.x * 256 + threadIdx.x;
    if (i < 256 * 512) {
        int n = i >> 9, k = i & 511;
        float v = (n < 64)  ? Wq[k * 64 + n]
                : (n < 128) ? Wk[k * 64 + (n - 64)]
                : (n < 192) ? Wv[k * 64 + (n - 128)] : 0.0f;
        WqkvT[i] = f2b(v);
    }
    if (i < 256)
        bqkv[i] = (i < 64) ? bq[i] : (i < 128) ? bk[i - 64] : (i < 192) ? bv[i - 128] : 0.0f;
}

// WoST bf16 [512][64]: WoST[e][k] = sum_h Wo[h*64+k][e]
__global__ __launch_bounds__(256) void wosumT_kernel(const float* __restrict__ Wo,
                                                     short* __restrict__ WoST) {
    int i = blockIdx.x * 256 + threadIdx.x;
    if (i >= 512 * 64) return;
    int e = i >> 6, k = i & 63;
    float s = 0.f;
#pragma unroll
    for (int h = 0; h < 8; ++h) s += Wo[(size_t)(h * 64 + k) * 512 + e];
    WoST[i] = f2b(s);
}

// Tiled transpose fp32[R][C] -> bf16[C][R]
__global__ __launch_bounds__(256) void transpose_b16(const float* __restrict__ in,
                                                     short* __restrict__ out,
                                                     int R, int C) {
    __shared__ float tile[32][33];
    int bx = blockIdx.x * 32;
    int by = blockIdx.y * 32;
    int tx = threadIdx.x & 31, ty = threadIdx.x >> 5;
#pragma unroll
    for (int i = 0; i < 32; i += 8)
        tile[ty + i][tx] = in[(size_t)(by + ty + i) * C + bx + tx];
    __syncthreads();
#pragma unroll
    for (int i = 0; i < 32; i += 8)
        out[(size_t)(bx + ty + i) * R + by + tx] = f2b(tile[tx][ty + i]);
}

// V slice of qkvb [16384][256] -> Vtg bf16 [8][64][2048]
__global__ __launch_bounds__(256) void vtrans_kernel(const short* __restrict__ qkvb,
                                                     short* __restrict__ Vtg) {
    __shared__ short tile[32][40];
    int sx = blockIdx.x * 32;          // seq offset
    int dy = blockIdx.y * 32;          // dim offset (0 or 32)
    int b  = blockIdx.z;
    int tx = threadIdx.x & 31, ty = threadIdx.x >> 5;   // ty 0..7
#pragma unroll
    for (int i = 0; i < 32; i += 8)
        tile[ty + i][tx] = qkvb[(size_t)(b * SS + sx + ty + i) * 256 + 128 + dy + tx];
    __syncthreads();
#pragma unroll
    for (int i = 0; i < 32; i += 8)
        Vtg[(size_t)(b * 64 + dy + ty + i) * SS + sx + tx] = tile[tx][ty + i];
}

// ---------------------------------------------------------------------------
// bf16 MFMA GEMM, 128x128 tile, BK=32, 256 thr = 4 waves (2x2), 4x4 frags.
// ---------------------------------------------------------------------------
__device__ __forceinline__ void async16(const void* g, void* l) {
    __builtin_amdgcn_global_load_lds(
        (const __attribute__((address_space(1))) void*)g,
        (__attribute__((address_space(3))) void*)l, 16, 0, 0);
}

template <bool RELU, int RESID, bool OUTBF>
__global__ __launch_bounds__(256) void gemm_mfma(const short* __restrict__ A,
                                                 const short* __restrict__ BT,
                                                 const float* __restrict__ bias,
                                                 const void* __restrict__ resid,
                                                 void* __restrict__ C,
                                                 int M, int N, int K) {
    __shared__ short As[128 * 32];
    __shared__ short Bs[128 * 32];
    const int t   = threadIdx.x;
    const int wv  = t >> 6;
    const int l   = t & 63;
    const int wr  = wv >> 1, wc = wv & 1;
    const int q   = l >> 4,  l16 = l & 15;
    const long m0 = (long)blockIdx.y * 128;
    const long n0 = (long)blockIdx.x * 128;

    f32x4 acc[4][4] = {};

    const int srow = wv * 16 + (l >> 2);
    const int kcol = (l & 3) * 8;

    for (int k0 = 0; k0 < K; k0 += 32) {
#pragma unroll
        for (int i = 0; i < 2; ++i) {
            const short* ga = A  + (m0 + srow + i * 64) * (long)K + k0 + kcol;
            const short* gb = BT + (n0 + srow + i * 64) * (long)K + k0 + kcol;
            async16(ga, &As[(wv * 16 + i * 64) * 32 + l * 8]);
            async16(gb, &Bs[(wv * 16 + i * 64) * 32 + l * 8]);
        }
        __syncthreads();
        short8 af[4], bfr[4];
#pragma unroll
        for (int i = 0; i < 4; ++i) {
            af[i]  = *(const short8*)&As[(wr * 64 + i * 16 + l16) * 32 + q * 8];
            bfr[i] = *(const short8*)&Bs[(wc * 64 + i * 16 + l16) * 32 + q * 8];
        }
#pragma unroll
        for (int mt = 0; mt < 4; ++mt)
#pragma unroll
            for (int nt = 0; nt < 4; ++nt)
                acc[mt][nt] = __builtin_amdgcn_mfma_f32_16x16x32_bf16(
                    af[mt], bfr[nt], acc[mt][nt], 0, 0, 0);
        __syncthreads();
    }
#pragma unroll
    for (int mt = 0; mt < 4; ++mt) {
        const long rowb = m0 + wr * 64 + mt * 16 + q * 4;
#pragma unroll
        for (int nt = 0; nt < 4; ++nt) {
            const long col = n0 + wc * 64 + nt * 16 + l16;
            const float bv = bias[col];
#pragma unroll
            for (int r = 0; r < 4; ++r) {
                const long idx = (rowb + r) * (long)N + col;
                float v = acc[mt][nt][r] + bv;
                if (RESID == 1) v += ((const float*)resid)[idx];
                if (RESID == 2) v += b2f(((const short*)resid)[idx]);
                if (RELU) v = fmaxf(v, 0.0f);
                if (OUTBF) ((short*)C)[idx] = f2b(v);
                else       ((float*)C)[idx] = v;
            }
        }
    }
}

// ---------------------------------------------------------------------------
// bf16 MFMA flash attention. Block = 64 q-rows (4 waves x 16), loops 2048 keys
// in 64-key tiles. Computes S^T = K.Q^T (softmax state scalar per lane),
// then O^T = V^T.P^T with P round-trip through wave-private LDS.
// qkvb: [16384][256] bf16 (q|k|v|pad); Vtg: [8][64][2048] bf16; head: [16384][64] bf16
// ---------------------------------------------------------------------------
__global__ __launch_bounds__(256) void attn_mfma(const short* __restrict__ qkvb,
                                                 const short* __restrict__ Vtg,
                                                 short* __restrict__ head) {
    const int b  = blockIdx.y;
    const int q0 = blockIdx.x * 64;
    const int t  = threadIdx.x;
    const int w  = t >> 6;
    const int l  = t & 63;
    const int l15 = l & 15, lq = l >> 4;
    const int l7  = l & 7,  l8 = l >> 3;

    __shared__ short Ks[64][72];        // [key][dim], pad 72 for bank spread
    __shared__ short Vs[64][72];        // [dim][key]
    __shared__ short Ps[4][16][68];     // per-wave P^T [qrow][key]

    // Q B-frags: lane holds Q[q0+w*16+l15][lq*8+j + 32*kc]
    short8 qf[2];
    {
        const short* qrow = qkvb + (size_t)(b * SS + q0 + w * 16 + l15) * 256;
        qf[0] = *(const short8*)(qrow + lq * 8);
        qf[1] = *(const short8*)(qrow + 32 + lq * 8);
    }

    f32x4 acc[4];
#pragma unroll
    for (int mt = 0; mt < 4; ++mt) acc[mt] = {0.f, 0.f, 0.f, 0.f};
    float m_i = -INFINITY, l_i = 0.f;
    const float sc = 0.0450712500463f;   // log2(e)/32

    // stage tile 0 into registers
    short8 kreg[2], vreg[2];
    {
        const short* kb = qkvb + (size_t)(b * SS) * 256 + 64;
        kreg[0] = *(const short8*)(kb + (size_t)(w * 8 + l8) * 256 + l7 * 8);
        kreg[1] = *(const short8*)(kb + (size_t)(32 + w * 8 + l8) * 256 + l7 * 8);
        const short* vb = Vtg + (size_t)b * 64 * SS;
        vreg[0] = *(const short8*)(vb + (size_t)(w * 8 + l8) * SS + l7 * 8);
        vreg[1] = *(const short8*)(vb + (size_t)(32 + w * 8 + l8) * SS + l7 * 8);
    }

    for (int kt = 0; kt < SS / 64; ++kt) {
        __syncthreads();               // previous compute done reading LDS
        *(short8*)&Ks[w * 8 + l8][l7 * 8]      = kreg[0];
        *(short8*)&Ks[32 + w * 8 + l8][l7 * 8] = kreg[1];
        *(short8*)&Vs[w * 8 + l8][l7 * 8]      = vreg[0];
        *(short8*)&Vs[32 + w * 8 + l8][l7 * 8] = vreg[1];
        if (kt + 1 < SS / 64) {        // prefetch next tile during compute
            const short* kb = qkvb + (size_t)(b * SS + (kt + 1) * 64) * 256 + 64;
            kreg[0] = *(const short8*)(kb + (size_t)(w * 8 + l8) * 256 + l7 * 8);
            kreg[1] = *(const short8*)(kb + (size_t)(32 + w * 8 + l8) * 256 + l7 * 8);
            const short* vb = Vtg + (size_t)b * 64 * SS + (kt + 1) * 64;
            vreg[0] = *(const short8*)(vb + (size_t)(w * 8 + l8) * SS + l7 * 8);
            vreg[1] = *(const short8*)(vb + (size_t)(32 + w * 8 + l8) * SS + l7 * 8);
        }
        __syncthreads();               // staged tile visible

        // S^T = K . Q^T : St[mt] covers keys mt*16.., qrows = this wave's 16
        f32x4 st[4];
#pragma unroll
        for (int mt = 0; mt < 4; ++mt) st[mt] = {0.f, 0.f, 0.f, 0.f};
#pragma unroll
        for (int kc = 0; kc < 2; ++kc)
#pragma unroll
            for (int mt = 0; mt < 4; ++mt) {
                short8 kf = *(const short8*)&Ks[mt * 16 + l15][kc * 32 + lq * 8];
                st[mt] = __builtin_amdgcn_mfma_f32_16x16x32_bf16(kf, qf[kc], st[mt], 0, 0, 0);
            }
        // online softmax (exp2 domain); lane owns qrow = l15, keys lq*4+r per tile
        float mx = m_i;
#pragma unroll
        for (int mt = 0; mt < 4; ++mt)
#pragma unroll
            for (int r = 0; r < 4; ++r) {
                st[mt][r] *= sc;
                mx = fmaxf(mx, st[mt][r]);
            }
        mx = fmaxf(mx, __shfl_xor(mx, 16));
        mx = fmaxf(mx, __shfl_xor(mx, 32));
        float alpha = exp2f(m_i - mx);
        float rs = 0.f;
#pragma unroll
        for (int mt = 0; mt < 4; ++mt) {
            s16x4 pk;
#pragma unroll
            for (int r = 0; r < 4; ++r) {
                float p = exp2f(st[mt][r] - mx);
                rs += p;
                pk[r] = f2b(p);
            }
            *(s16x4*)&Ps[w][l15][mt * 16 + lq * 4] = pk;
        }
        rs += __shfl_xor(rs, 16);
        rs += __shfl_xor(rs, 32);
        l_i = l_i * alpha + rs;
        m_i = mx;
#pragma unroll
        for (int mt = 0; mt < 4; ++mt)
#pragma unroll
            for (int r = 0; r < 4; ++r) acc[mt][r] *= alpha;

        // O^T += V^T . P^T
#pragma unroll
        for (int kc = 0; kc < 2; ++kc) {
            s16x4 p0 = *(const s16x4*)&Ps[w][l15][kc * 32 + lq * 8];
            s16x4 p1 = *(const s16x4*)&Ps[w][l15][kc * 32 + lq * 8 + 4];
            short8 pf = __builtin_shufflevector(p0, p1, 0, 1, 2, 3, 4, 5, 6, 7);
#pragma unroll
            for (int mt = 0; mt < 4; ++mt) {
                short8 vf = *(const short8*)&Vs[mt * 16 + l15][kc * 32 + lq * 8];
                acc[mt] = __builtin_amdgcn_mfma_f32_16x16x32_bf16(vf, pf, acc[mt], 0, 0, 0);
            }
        }
    }
    // epilogue: head[qrow][dim] = O^T / l
    float inv = 1.0f / l_i;
    short* out = head + (size_t)(b * SS + q0 + w * 16 + l15) * 64;
#pragma unroll
    for (int mt = 0; mt < 4; ++mt) {
        s16x4 o;
#pragma unroll
        for (int r = 0; r < 4; ++r) o[r] = f2b(acc[mt][r] * inv);
        *(s16x4*)&out[mt * 16 + lq * 4] = o;
    }
}

// ---------------------------------------------------------------------------
// Whole-tensor LayerNorm
// ---------------------------------------------------------------------------
__global__ __launch_bounds__(256) void reduce_kernel(const float* __restrict__ x,
                                                     double* __restrict__ red, int n) {
    double s = 0.0, sq = 0.0;
    for (int i = blockIdx.x * blockDim.x + threadIdx.x; i < n;
         i += gridDim.x * blockDim.x) {
        float v = x[i];
        s += (double)v;
        sq += (double)v * (double)v;
    }
    for (int o = 32; o; o >>= 1) {
        s  += __shfl_down(s, o);
        sq += __shfl_down(sq, o);
    }
    __shared__ double ls[4], lsq[4];
    int w = threadIdx.x >> 6, lane = threadIdx.x & 63;
    if (lane == 0) { ls[w] = s; lsq[w] = sq; }
    __syncthreads();
    if (threadIdx.x == 0) {
        atomicAdd(&red[0], ls[0] + ls[1] + ls[2] + ls[3]);
        atomicAdd(&red[1], lsq[0] + lsq[1] + lsq[2] + lsq[3]);
    }
}

__global__ __launch_bounds__(256) void lnorm2_kernel(const float* __restrict__ in,
                                                     float* __restrict__ out32,
                                                     short* __restrict__ out16,
                                                     const double* __restrict__ red,
                                                     int n) {
    double mean = red[0] / n;
    double var  = red[1] / n - mean * mean;
    float mu   = (float)mean;
    float rstd = (float)(1.0 / sqrt(var + LN_EPS));
    for (int i = blockIdx.x * blockDim.x + threadIdx.x; i < n;
         i += gridDim.x * blockDim.x) {
        float v = (in[i] - mu) * rstd;
        if (out32) out32[i] = v;
        if (out16) out16[i] = f2b(v);
    }
}

// ---------------------------------------------------------------------------
extern "C" void kernel_launch(void* const* d_in, const int* in_sizes, int n_in,
                              void* d_out, int out_size, void* d_ws, size_t ws_size,
                              hipStream_t stream) {
    const int*   ids = (const int*)d_in[0];
    const float* emb = (const float*)d_in[1];
    const float* Wq  = (const float*)d_in[2];
    const float* bq  = (const float*)d_in[3];
    const float* Wk  = (const float*)d_in[4];
    const float* bk  = (const float*)d_in[5];
    const float* Wv  = (const float*)d_in[6];
    const float* bv  = (const float*)d_in[7];
    const float* Wo  = (const float*)d_in[8];
    const float* bo  = (const float*)d_in[9];
    const float* W1  = (const float*)d_in[10];
    const float* b1  = (const float*)d_in[11];
    const float* W2  = (const float*)d_in[12];
    const float* b2  = (const float*)d_in[13];

    float* x = (float*)d_out;                        // [16384][512] fp32

    // Workspace layout (bytes):
    // [0..8M)    qkvb  bf16 [16384][256]      -- dead during FF
    // [8..10M)   Vtg   bf16 [8][64][2048]     -- dead during FF
    // [10..12M)  head  bf16 [16384][64]       -- dead during FF
    // [12..28M)  xb    bf16 [16384][512]      -- dead during FF (LN2 rewrites)
    // [0..32M)   hch   bf16 [8192][2048]      -- FF phase only (aliases above)
    // [32..48M)  x1b   bf16 [16384][512]      -- live through FF
    // [48M..)    weights + red
    char* w = (char*)d_ws;
    short*  qkvb  = (short*)(w + 0);
    short*  Vtg   = (short*)(w + 8388608);
    short*  head  = (short*)(w + 10485760);
    short*  xb    = (short*)(w + 12582912);
    short*  hch   = (short*)(w + 0);
    short*  x1b   = (short*)(w + 33554432);
    short*  WqkvT = (short*)(w + 50331648);
    float*  bqkv  = (float*)(w + 50593792);
    short*  WoST  = (short*)(w + 50594816);
    short*  W1T   = (short*)(w + 50660352);
    short*  W2T   = (short*)(w + 52757504);
    double* red   = (double*)(w + 54854656);         // 12 slots x 2 doubles

    // ---- setup (once per launch) ----
    packqkvT_kernel<<<(256 * 512 + 255) / 256, 256, 0, stream>>>(Wq, Wk, Wv, bq, bk, bv, WqkvT, bqkv);
    wosumT_kernel<<<(512 * 64 + 255) / 256, 256, 0, stream>>>(Wo, WoST);
    transpose_b16<<<dim3(2048 / 32, 512 / 32), 256, 0, stream>>>(W1, W1T, 512, 2048);
    transpose_b16<<<dim3(512 / 32, 2048 / 32), 256, 0, stream>>>(W2, W2T, 2048, 512);
    embed_kernel<<<NTOT / 256, 256, 0, stream>>>(ids, emb, x, xb, red);

    for (int rep = 0; rep < 6; ++rep) {
        double* red1 = red + 4 * rep;
        double* red2 = red + 4 * rep + 2;
        // QKV: xb @ WqkvT -> qkvb bf16 [16384][256]
        gemm_mfma<false, 0, true><<<dim3(2, 128), 256, 0, stream>>>(
            xb, WqkvT, bqkv, nullptr, qkvb, ROWS, 256, DM);
        // V transpose: qkvb -> Vtg [8][64][2048]
        vtrans_kernel<<<dim3(SS / 32, 2, BB), 256, 0, stream>>>(qkvb, Vtg);
        // flash attention -> head bf16 [16384][64]
        attn_mfma<<<dim3(SS / 64, BB), 256, 0, stream>>>(qkvb, Vtg, head);
        // out-proj: head @ WoST + bo + x -> x (fp32, in place)
        gemm_mfma<false, 1, false><<<dim3(4, 128), 256, 0, stream>>>(
            head, WoST, bo, x, x, ROWS, DM, DK);
        // LN1: x -> x1b (bf16)
        reduce_kernel<<<1024, 256, 0, stream>>>(x, red1, NTOT);
        lnorm2_kernel<<<4096, 256, 0, stream>>>(x, nullptr, x1b, red1, NTOT);
        // FF in 2 row-chunks of 8192 (hidden chunk aliases dead buffers)
        for (int c = 0; c < 2; ++c) {
            const size_t off = (size_t)c * 8192 * DM;
            gemm_mfma<true, 0, true><<<dim3(16, 64), 256, 0, stream>>>(
                x1b + off, W1T, b1, nullptr, hch, 8192, DFF, DM);
            gemm_mfma<false, 2, false><<<dim3(4, 64), 256, 0, stream>>>(
                hch, W2T, b2, x1b + off, x + off, 8192, DM, DFF);
        }
        // LN2: x -> x (fp32) + xb (bf16, next rep's QKV input)
        reduce_kernel<<<1024, 256, 0, stream>>>(x, red2, NTOT);
        lnorm2_kernel<<<4096, 256, 0, stream>>>(x, x, xb, red2, NTOT);
    }
}

// Round 5
// 1535.408 us; speedup vs baseline: 6.0407x; 1.3746x over previous
//
#include <hip/hip_runtime.h>
#include <math.h>

// Problem constants
#define BB 8
#define SS 2048
#define DM 512
#define DK 64
#define DFF 2048
#define ROWS (BB*SS)          // 16384
#define NTOT (ROWS*DM)        // 8388608
#define LN_EPS 1e-5
#define PAD_IDX 0

typedef __attribute__((ext_vector_type(8))) short short8;
typedef __attribute__((ext_vector_type(4))) short s16x4;
typedef __attribute__((ext_vector_type(4))) float f32x4;

__device__ __forceinline__ short f2b(float f) {        // fp32 -> bf16 (RNE)
    unsigned u = __float_as_uint(f);
    unsigned r = (u + 0x7fffu + ((u >> 16) & 1u)) >> 16;
    return (short)r;
}
__device__ __forceinline__ float b2f(short s) {        // bf16 -> fp32
    return __uint_as_float(((unsigned)(unsigned short)s) << 16);
}

// ---------------------------------------------------------------------------
// Embedding + positional encoding -> x fp32 AND xb bf16; zero LN slots
// ---------------------------------------------------------------------------
__global__ __launch_bounds__(256) void embed_kernel(const int* __restrict__ ids,
                                                    const float* __restrict__ emb,
                                                    float* __restrict__ x,
                                                    short* __restrict__ xb,
                                                    double* __restrict__ red) {
    int idx = blockIdx.x * 256 + threadIdx.x;
    if (idx < 24) red[idx] = 0.0;              // 12 LN slots x (sum,sumsq)
    if (idx >= NTOT) return;
    int d   = idx & (DM - 1);
    int row = idx >> 9;
    int s   = row & (SS - 1);
    int id  = ids[row];
    float e = (id != PAD_IDX) ? emb[(size_t)id * DM + d] : 0.0f;
    float ex  = 2.0f * (float)d / 512.0f;
    float div = powf(10000.0f, ex);
    float arg = (float)s / div;
    float pe  = (d & 1) ? cosf(arg) : sinf(arg);
    float v = e + pe;
    x[idx]  = v;
    xb[idx] = f2b(v);
}

// ---------------------------------------------------------------------------
// Weight packing: WqkvT bf16 [256][512] (rows 192..255 zero) + bqkv fp32[256]
// ---------------------------------------------------------------------------
__global__ __launch_bounds__(256) void packqkvT_kernel(const float* __restrict__ Wq,
                                                       const float* __restrict__ Wk,
                                                       const float* __restrict__ Wv,
                                                       const float* __restrict__ bq,
                                                       const float* __restrict__ bk,
                                                       const float* __restrict__ bv,
                                                       short* __restrict__ WqkvT,
                                                       float* __restrict__ bqkv) {
    int i = blockIdx.x * 256 + threadIdx.x;
    if (i < 256 * 512) {
        int n = i >> 9, k = i & 511;
        float v = (n < 64)  ? Wq[k * 64 + n]
                : (n < 128) ? Wk[k * 64 + (n - 64)]
                : (n < 192) ? Wv[k * 64 + (n - 128)] : 0.0f;
        WqkvT[i] = f2b(v);
    }
    if (i < 256)
        bqkv[i] = (i < 64) ? bq[i] : (i < 128) ? bk[i - 64] : (i < 192) ? bv[i - 128] : 0.0f;
}

// WoST bf16 [512][64]: WoST[e][k] = sum_h Wo[h*64+k][e]
__global__ __launch_bounds__(256) void wosumT_kernel(const float* __restrict__ Wo,
                                                     short* __restrict__ WoST) {
    int i = blockIdx.x * 256 + threadIdx.x;
    if (i >= 512 * 64) return;
    int e = i >> 6, k = i & 63;
    float s = 0.f;
#pragma unroll
    for (int h = 0; h < 8; ++h) s += Wo[(size_t)(h * 64 + k) * 512 + e];
    WoST[i] = f2b(s);
}

// Tiled transpose fp32[R][C] -> bf16[C][R]
__global__ __launch_bounds__(256) void transpose_b16(const float* __restrict__ in,
                                                     short* __restrict__ out,
                                                     int R, int C) {
    __shared__ float tile[32][33];
    int bx = blockIdx.x * 32;
    int by = blockIdx.y * 32;
    int tx = threadIdx.x & 31, ty = threadIdx.x >> 5;
#pragma unroll
    for (int i = 0; i < 32; i += 8)
        tile[ty + i][tx] = in[(size_t)(by + ty + i) * C + bx + tx];
    __syncthreads();
#pragma unroll
    for (int i = 0; i < 32; i += 8)
        out[(size_t)(bx + ty + i) * R + by + tx] = f2b(tile[tx][ty + i]);
}

// V slice of qkvb [16384][256] -> Vtg bf16 [8][64][2048]
__global__ __launch_bounds__(256) void vtrans_kernel(const short* __restrict__ qkvb,
                                                     short* __restrict__ Vtg) {
    __shared__ short tile[32][40];
    int sx = blockIdx.x * 32;          // seq offset
    int dy = blockIdx.y * 32;          // dim offset (0 or 32)
    int b  = blockIdx.z;
    int tx = threadIdx.x & 31, ty = threadIdx.x >> 5;   // ty 0..7
#pragma unroll
    for (int i = 0; i < 32; i += 8)
        tile[ty + i][tx] = qkvb[(size_t)(b * SS + sx + ty + i) * 256 + 128 + dy + tx];
    __syncthreads();
#pragma unroll
    for (int i = 0; i < 32; i += 8)
        Vtg[(size_t)(b * 64 + dy + ty + i) * SS + sx + tx] = tile[tx][ty + i];
}

// ---------------------------------------------------------------------------
// bf16 MFMA GEMM, 128x128 tile, BK=32, 256 thr = 4 waves (2x2), 4x4 frags.
// Grid: blockIdx.x = M-tile (XCD affinity: bi%8 = m%8), blockIdx.y = N-tile.
// STATS: epilogue accumulates sum/sumsq of outputs into red (whole-tensor LN).
// ---------------------------------------------------------------------------
__device__ __forceinline__ void async16(const void* g, void* l) {
    __builtin_amdgcn_global_load_lds(
        (const __attribute__((address_space(1))) void*)g,
        (__attribute__((address_space(3))) void*)l, 16, 0, 0);
}

template <bool RELU, int RESID, bool OUTBF, bool STATS>
__global__ __launch_bounds__(256) void gemm_mfma(const short* __restrict__ A,
                                                 const short* __restrict__ BT,
                                                 const float* __restrict__ bias,
                                                 const void* __restrict__ resid,
                                                 void* __restrict__ C,
                                                 double* __restrict__ red,
                                                 int M, int N, int K) {
    __shared__ short As[128 * 32];
    __shared__ short Bs[128 * 32];
    const int t   = threadIdx.x;
    const int wv  = t >> 6;
    const int l   = t & 63;
    const int wr  = wv >> 1, wc = wv & 1;
    const int q   = l >> 4,  l16 = l & 15;
    const long m0 = (long)blockIdx.x * 128;
    const long n0 = (long)blockIdx.y * 128;

    f32x4 acc[4][4] = {};

    const int srow = wv * 16 + (l >> 2);
    const int kcol = (l & 3) * 8;

    for (int k0 = 0; k0 < K; k0 += 32) {
#pragma unroll
        for (int i = 0; i < 2; ++i) {
            const short* ga = A  + (m0 + srow + i * 64) * (long)K + k0 + kcol;
            const short* gb = BT + (n0 + srow + i * 64) * (long)K + k0 + kcol;
            async16(ga, &As[(wv * 16 + i * 64) * 32 + l * 8]);
            async16(gb, &Bs[(wv * 16 + i * 64) * 32 + l * 8]);
        }
        __syncthreads();
        short8 af[4], bfr[4];
#pragma unroll
        for (int i = 0; i < 4; ++i) {
            af[i]  = *(const short8*)&As[(wr * 64 + i * 16 + l16) * 32 + q * 8];
            bfr[i] = *(const short8*)&Bs[(wc * 64 + i * 16 + l16) * 32 + q * 8];
        }
#pragma unroll
        for (int mt = 0; mt < 4; ++mt)
#pragma unroll
            for (int nt = 0; nt < 4; ++nt)
                acc[mt][nt] = __builtin_amdgcn_mfma_f32_16x16x32_bf16(
                    af[mt], bfr[nt], acc[mt][nt], 0, 0, 0);
        __syncthreads();
    }
    float s = 0.f, sq = 0.f;
#pragma unroll
    for (int mt = 0; mt < 4; ++mt) {
        const long rowb = m0 + wr * 64 + mt * 16 + q * 4;
#pragma unroll
        for (int nt = 0; nt < 4; ++nt) {
            const long col = n0 + wc * 64 + nt * 16 + l16;
            const float bv = bias[col];
#pragma unroll
            for (int r = 0; r < 4; ++r) {
                const long idx = (rowb + r) * (long)N + col;
                float v = acc[mt][nt][r] + bv;
                if (RESID == 1) v += ((const float*)resid)[idx];
                if (RESID == 2) v += b2f(((const short*)resid)[idx]);
                if (RELU) v = fmaxf(v, 0.0f);
                if (STATS) { s += v; sq += v * v; }
                if (OUTBF) ((short*)C)[idx] = f2b(v);
                else       ((float*)C)[idx] = v;
            }
        }
    }
    if (STATS) {
#pragma unroll
        for (int o = 32; o; o >>= 1) {
            s  += __shfl_down(s, o);
            sq += __shfl_down(sq, o);
        }
        float* sm = (float*)As;        // K-loop fully done; safe to reuse
        if (l == 0) { sm[wv] = s; sm[4 + wv] = sq; }
        __syncthreads();
        if (t == 0) {
            atomicAdd(&red[0], (double)(sm[0] + sm[1] + sm[2] + sm[3]));
            atomicAdd(&red[1], (double)(sm[4] + sm[5] + sm[6] + sm[7]));
        }
    }
}

// ---------------------------------------------------------------------------
// bf16 MFMA flash attention (unchanged from round 4).
// ---------------------------------------------------------------------------
__global__ __launch_bounds__(256) void attn_mfma(const short* __restrict__ qkvb,
                                                 const short* __restrict__ Vtg,
                                                 short* __restrict__ head) {
    const int b  = blockIdx.y;
    const int q0 = blockIdx.x * 64;
    const int t  = threadIdx.x;
    const int w  = t >> 6;
    const int l  = t & 63;
    const int l15 = l & 15, lq = l >> 4;
    const int l7  = l & 7,  l8 = l >> 3;

    __shared__ short Ks[64][72];
    __shared__ short Vs[64][72];
    __shared__ short Ps[4][16][68];

    short8 qf[2];
    {
        const short* qrow = qkvb + (size_t)(b * SS + q0 + w * 16 + l15) * 256;
        qf[0] = *(const short8*)(qrow + lq * 8);
        qf[1] = *(const short8*)(qrow + 32 + lq * 8);
    }

    f32x4 acc[4];
#pragma unroll
    for (int mt = 0; mt < 4; ++mt) acc[mt] = {0.f, 0.f, 0.f, 0.f};
    float m_i = -INFINITY, l_i = 0.f;
    const float sc = 0.0450712500463f;   // log2(e)/32

    short8 kreg[2], vreg[2];
    {
        const short* kb = qkvb + (size_t)(b * SS) * 256 + 64;
        kreg[0] = *(const short8*)(kb + (size_t)(w * 8 + l8) * 256 + l7 * 8);
        kreg[1] = *(const short8*)(kb + (size_t)(32 + w * 8 + l8) * 256 + l7 * 8);
        const short* vb = Vtg + (size_t)b * 64 * SS;
        vreg[0] = *(const short8*)(vb + (size_t)(w * 8 + l8) * SS + l7 * 8);
        vreg[1] = *(const short8*)(vb + (size_t)(32 + w * 8 + l8) * SS + l7 * 8);
    }

    for (int kt = 0; kt < SS / 64; ++kt) {
        __syncthreads();
        *(short8*)&Ks[w * 8 + l8][l7 * 8]      = kreg[0];
        *(short8*)&Ks[32 + w * 8 + l8][l7 * 8] = kreg[1];
        *(short8*)&Vs[w * 8 + l8][l7 * 8]      = vreg[0];
        *(short8*)&Vs[32 + w * 8 + l8][l7 * 8] = vreg[1];
        if (kt + 1 < SS / 64) {
            const short* kb = qkvb + (size_t)(b * SS + (kt + 1) * 64) * 256 + 64;
            kreg[0] = *(const short8*)(kb + (size_t)(w * 8 + l8) * 256 + l7 * 8);
            kreg[1] = *(const short8*)(kb + (size_t)(32 + w * 8 + l8) * 256 + l7 * 8);
            const short* vb = Vtg + (size_t)b * 64 * SS + (kt + 1) * 64;
            vreg[0] = *(const short8*)(vb + (size_t)(w * 8 + l8) * SS + l7 * 8);
            vreg[1] = *(const short8*)(vb + (size_t)(32 + w * 8 + l8) * SS + l7 * 8);
        }
        __syncthreads();

        f32x4 st[4];
#pragma unroll
        for (int mt = 0; mt < 4; ++mt) st[mt] = {0.f, 0.f, 0.f, 0.f};
#pragma unroll
        for (int kc = 0; kc < 2; ++kc)
#pragma unroll
            for (int mt = 0; mt < 4; ++mt) {
                short8 kf = *(const short8*)&Ks[mt * 16 + l15][kc * 32 + lq * 8];
                st[mt] = __builtin_amdgcn_mfma_f32_16x16x32_bf16(kf, qf[kc], st[mt], 0, 0, 0);
            }
        float mx = m_i;
#pragma unroll
        for (int mt = 0; mt < 4; ++mt)
#pragma unroll
            for (int r = 0; r < 4; ++r) {
                st[mt][r] *= sc;
                mx = fmaxf(mx, st[mt][r]);
            }
        mx = fmaxf(mx, __shfl_xor(mx, 16));
        mx = fmaxf(mx, __shfl_xor(mx, 32));
        float alpha = exp2f(m_i - mx);
        float rs = 0.f;
#pragma unroll
        for (int mt = 0; mt < 4; ++mt) {
            s16x4 pk;
#pragma unroll
            for (int r = 0; r < 4; ++r) {
                float p = exp2f(st[mt][r] - mx);
                rs += p;
                pk[r] = f2b(p);
            }
            *(s16x4*)&Ps[w][l15][mt * 16 + lq * 4] = pk;
        }
        rs += __shfl_xor(rs, 16);
        rs += __shfl_xor(rs, 32);
        l_i = l_i * alpha + rs;
        m_i = mx;
#pragma unroll
        for (int mt = 0; mt < 4; ++mt)
#pragma unroll
            for (int r = 0; r < 4; ++r) acc[mt][r] *= alpha;

#pragma unroll
        for (int kc = 0; kc < 2; ++kc) {
            s16x4 p0 = *(const s16x4*)&Ps[w][l15][kc * 32 + lq * 8];
            s16x4 p1 = *(const s16x4*)&Ps[w][l15][kc * 32 + lq * 8 + 4];
            short8 pf = __builtin_shufflevector(p0, p1, 0, 1, 2, 3, 4, 5, 6, 7);
#pragma unroll
            for (int mt = 0; mt < 4; ++mt) {
                short8 vf = *(const short8*)&Vs[mt * 16 + l15][kc * 32 + lq * 8];
                acc[mt] = __builtin_amdgcn_mfma_f32_16x16x32_bf16(vf, pf, acc[mt], 0, 0, 0);
            }
        }
    }
    float inv = 1.0f / l_i;
    short* out = head + (size_t)(b * SS + q0 + w * 16 + l15) * 64;
#pragma unroll
    for (int mt = 0; mt < 4; ++mt) {
        s16x4 o;
#pragma unroll
        for (int r = 0; r < 4; ++r) o[r] = f2b(acc[mt][r] * inv);
        *(s16x4*)&out[mt * 16 + lq * 4] = o;
    }
}

// ---------------------------------------------------------------------------
// Whole-tensor LN normalize (stats already in red via GEMM epilogues)
// ---------------------------------------------------------------------------
__global__ __launch_bounds__(256) void lnorm2_kernel(const float* __restrict__ in,
                                                     float* __restrict__ out32,
                                                     short* __restrict__ out16,
                                                     const double* __restrict__ red,
                                                     int n) {
    double mean = red[0] / n;
    double var  = red[1] / n - mean * mean;
    float mu   = (float)mean;
    float rstd = (float)(1.0 / sqrt(var + LN_EPS));
    for (int i = blockIdx.x * blockDim.x + threadIdx.x; i < n;
         i += gridDim.x * blockDim.x) {
        float v = (in[i] - mu) * rstd;
        if (out32) out32[i] = v;
        if (out16) out16[i] = f2b(v);
    }
}

// ---------------------------------------------------------------------------
extern "C" void kernel_launch(void* const* d_in, const int* in_sizes, int n_in,
                              void* d_out, int out_size, void* d_ws, size_t ws_size,
                              hipStream_t stream) {
    const int*   ids = (const int*)d_in[0];
    const float* emb = (const float*)d_in[1];
    const float* Wq  = (const float*)d_in[2];
    const float* bq  = (const float*)d_in[3];
    const float* Wk  = (const float*)d_in[4];
    const float* bk  = (const float*)d_in[5];
    const float* Wv  = (const float*)d_in[6];
    const float* bv  = (const float*)d_in[7];
    const float* Wo  = (const float*)d_in[8];
    const float* bo  = (const float*)d_in[9];
    const float* W1  = (const float*)d_in[10];
    const float* b1  = (const float*)d_in[11];
    const float* W2  = (const float*)d_in[12];
    const float* b2  = (const float*)d_in[13];

    float* x = (float*)d_out;                        // [16384][512] fp32
    char* w = (char*)d_ws;

    const bool big = ws_size >= (size_t)85 * 1024 * 1024;

    short *xb, *qkvb, *Vtg, *head, *x1b, *hch, *WqkvT, *WoST, *W1T, *W2T;
    float* bqkv; double* red;

    if (big) {
        // hch [0,64M) full [16384][2048]; dead-during-FF buffers alias inside.
        hch   = (short*)(w + 0);
        xb    = (short*)(w + 0);                     // 16 MB (live LN2->QKV)
        qkvb  = (short*)(w + 16777216);              //  8 MB (live QKV->attn)
        Vtg   = (short*)(w + 25165824);              //  2 MB
        head  = (short*)(w + 27262976);              //  2 MB (live attn->outproj)
        x1b   = (short*)(w + 67108864);              // 16 MB (live LN1->FF2)
        WqkvT = (short*)(w + 83886080);
        bqkv  = (float*)(w + 84148224);
        WoST  = (short*)(w + 84149248);
        W1T   = (short*)(w + 84215808);
        W2T   = (short*)(w + 86312960);
        red   = (double*)(w + 88410112);
    } else {
        // round-4 chunked layout
        hch   = (short*)(w + 0);                     // [8192][2048] per chunk
        qkvb  = (short*)(w + 0);
        Vtg   = (short*)(w + 8388608);
        head  = (short*)(w + 10485760);
        xb    = (short*)(w + 12582912);
        x1b   = (short*)(w + 33554432);
        WqkvT = (short*)(w + 50331648);
        bqkv  = (float*)(w + 50593792);
        WoST  = (short*)(w + 50594816);
        W1T   = (short*)(w + 50660352);
        W2T   = (short*)(w + 52757504);
        red   = (double*)(w + 54854656);
    }

    // ---- setup (once per launch) ----
    packqkvT_kernel<<<(256 * 512 + 255) / 256, 256, 0, stream>>>(Wq, Wk, Wv, bq, bk, bv, WqkvT, bqkv);
    wosumT_kernel<<<(512 * 64 + 255) / 256, 256, 0, stream>>>(Wo, WoST);
    transpose_b16<<<dim3(2048 / 32, 512 / 32), 256, 0, stream>>>(W1, W1T, 512, 2048);
    transpose_b16<<<dim3(512 / 32, 2048 / 32), 256, 0, stream>>>(W2, W2T, 2048, 512);
    embed_kernel<<<NTOT / 256, 256, 0, stream>>>(ids, emb, x, xb, red);

    for (int rep = 0; rep < 6; ++rep) {
        double* red1 = red + 4 * rep;
        double* red2 = red + 4 * rep + 2;
        // QKV: xb @ WqkvT -> qkvb bf16 [16384][256]
        gemm_mfma<false, 0, true, false><<<dim3(128, 2), 256, 0, stream>>>(
            xb, WqkvT, bqkv, nullptr, qkvb, nullptr, ROWS, 256, DM);
        // V transpose: qkvb -> Vtg [8][64][2048]
        vtrans_kernel<<<dim3(SS / 32, 2, BB), 256, 0, stream>>>(qkvb, Vtg);
        // flash attention -> head bf16 [16384][64]
        attn_mfma<<<dim3(SS / 64, BB), 256, 0, stream>>>(qkvb, Vtg, head);
        // out-proj: head @ WoST + bo + x -> x; fused LN1 stats -> red1
        gemm_mfma<false, 1, false, true><<<dim3(128, 4), 256, 0, stream>>>(
            head, WoST, bo, x, x, red1, ROWS, DM, DK);
        // LN1 normalize: x -> x1b (bf16)
        lnorm2_kernel<<<4096, 256, 0, stream>>>(x, nullptr, x1b, red1, NTOT);
        if (big) {
            gemm_mfma<true, 0, true, false><<<dim3(128, 16), 256, 0, stream>>>(
                x1b, W1T, b1, nullptr, hch, nullptr, ROWS, DFF, DM);
            gemm_mfma<false, 2, false, true><<<dim3(128, 4), 256, 0, stream>>>(
                hch, W2T, b2, x1b, x, red2, ROWS, DM, DFF);
        } else {
            for (int c = 0; c < 2; ++c) {
                const size_t off = (size_t)c * 8192 * DM;
                gemm_mfma<true, 0, true, false><<<dim3(64, 16), 256, 0, stream>>>(
                    x1b + off, W1T, b1, nullptr, hch, nullptr, 8192, DFF, DM);
                gemm_mfma<false, 2, false, true><<<dim3(64, 4), 256, 0, stream>>>(
                    hch, W2T, b2, x1b + off, x + off, red2, 8192, DM, DFF);
            }
        }
        // LN2 normalize: x -> x (fp32) + xb (bf16, next rep's QKV input)
        lnorm2_kernel<<<4096, 256, 0, stream>>>(x, x, xb, red2, NTOT);
    }
}

// Round 6
// 1505.267 us; speedup vs baseline: 6.1617x; 1.0200x over previous
//
#include <hip/hip_runtime.h>
#include <math.h>

// Problem constants
#define BB 8
#define SS 2048
#define DM 512
#define DK 64
#define DFF 2048
#define ROWS (BB*SS)          // 16384
#define NTOT (ROWS*DM)        // 8388608
#define LN_EPS 1e-5
#define PAD_IDX 0

typedef __attribute__((ext_vector_type(8))) short short8;
typedef __attribute__((ext_vector_type(4))) short s16x4;
typedef __attribute__((ext_vector_type(4))) float f32x4;

__device__ __forceinline__ short f2b(float f) {        // fp32 -> bf16 (RNE)
    unsigned u = __float_as_uint(f);
    unsigned r = (u + 0x7fffu + ((u >> 16) & 1u)) >> 16;
    return (short)r;
}
__device__ __forceinline__ float b2f(short s) {        // bf16 -> fp32
    return __uint_as_float(((unsigned)(unsigned short)s) << 16);
}

// ---------------------------------------------------------------------------
// Embedding + positional encoding -> trunk T1 (bf16); zero LN stat slots
// ---------------------------------------------------------------------------
__global__ __launch_bounds__(256) void embed_kernel(const int* __restrict__ ids,
                                                    const float* __restrict__ emb,
                                                    short* __restrict__ T1,
                                                    double* __restrict__ red) {
    int idx = blockIdx.x * 256 + threadIdx.x;
    if (idx < 24) red[idx] = 0.0;              // 12 LN slots x (sum,sumsq)
    if (idx >= NTOT) return;
    int d   = idx & (DM - 1);
    int row = idx >> 9;
    int s   = row & (SS - 1);
    int id  = ids[row];
    float e = (id != PAD_IDX) ? emb[(size_t)id * DM + d] : 0.0f;
    float ex  = 2.0f * (float)d / 512.0f;
    float div = powf(10000.0f, ex);
    float arg = (float)s / div;
    float pe  = (d & 1) ? cosf(arg) : sinf(arg);
    T1[idx] = f2b(e + pe);
}

// ---------------------------------------------------------------------------
// Weight packing: WqkvT bf16 [256][512] (rows 192..255 zero) + bqkv fp32[256]
// ---------------------------------------------------------------------------
__global__ __launch_bounds__(256) void packqkvT_kernel(const float* __restrict__ Wq,
                                                       const float* __restrict__ Wk,
                                                       const float* __restrict__ Wv,
                                                       const float* __restrict__ bq,
                                                       const float* __restrict__ bk,
                                                       const float* __restrict__ bv,
                                                       short* __restrict__ WqkvT,
                                                       float* __restrict__ bqkv) {
    int i = blockIdx.x * 256 + threadIdx.x;
    if (i < 256 * 512) {
        int n = i >> 9, k = i & 511;
        float v = (n < 64)  ? Wq[k * 64 + n]
                : (n < 128) ? Wk[k * 64 + (n - 64)]
                : (n < 192) ? Wv[k * 64 + (n - 128)] : 0.0f;
        WqkvT[i] = f2b(v);
    }
    if (i < 256)
        bqkv[i] = (i < 64) ? bq[i] : (i < 128) ? bk[i - 64] : (i < 192) ? bv[i - 128] : 0.0f;
}

// WoST bf16 [512][64]: WoST[e][k] = sum_h Wo[h*64+k][e]
__global__ __launch_bounds__(256) void wosumT_kernel(const float* __restrict__ Wo,
                                                     short* __restrict__ WoST) {
    int i = blockIdx.x * 256 + threadIdx.x;
    if (i >= 512 * 64) return;
    int e = i >> 6, k = i & 63;
    float s = 0.f;
#pragma unroll
    for (int h = 0; h < 8; ++h) s += Wo[(size_t)(h * 64 + k) * 512 + e];
    WoST[i] = f2b(s);
}

// Tiled transpose fp32[R][C] -> bf16[C][R]
__global__ __launch_bounds__(256) void transpose_b16(const float* __restrict__ in,
                                                     short* __restrict__ out,
                                                     int R, int C) {
    __shared__ float tile[32][33];
    int bx = blockIdx.x * 32;
    int by = blockIdx.y * 32;
    int tx = threadIdx.x & 31, ty = threadIdx.x >> 5;
#pragma unroll
    for (int i = 0; i < 32; i += 8)
        tile[ty + i][tx] = in[(size_t)(by + ty + i) * C + bx + tx];
    __syncthreads();
#pragma unroll
    for (int i = 0; i < 32; i += 8)
        out[(size_t)(bx + ty + i) * R + by + tx] = f2b(tile[tx][ty + i]);
}

// Column sums of bf16 weights (for LN folding):
// csq[n<256] = sum_k WqkvT[n][k]; csw1[n<2048] = sum_k W1T[n][k]
__global__ __launch_bounds__(256) void colsum_kernel(const short* __restrict__ WqkvT,
                                                     const short* __restrict__ W1T,
                                                     float* __restrict__ csq,
                                                     float* __restrict__ csw1) {
    int i = blockIdx.x * 256 + threadIdx.x;
    if (i < 256) {
        const short* p = WqkvT + (size_t)i * 512;
        float s = 0.f;
        for (int k = 0; k < 512; ++k) s += b2f(p[k]);
        csq[i] = s;
    } else if (i < 2304) {
        int n = i - 256;
        const short* p = W1T + (size_t)n * 512;
        float s = 0.f;
        for (int k = 0; k < 512; ++k) s += b2f(p[k]);
        csw1[n] = s;
    }
}

// V slice of qkvb [16384][256] -> Vtg bf16 [8][64][2048]
__global__ __launch_bounds__(256) void vtrans_kernel(const short* __restrict__ qkvb,
                                                     short* __restrict__ Vtg) {
    __shared__ short tile[32][40];
    int sx = blockIdx.x * 32;
    int dy = blockIdx.y * 32;
    int b  = blockIdx.z;
    int tx = threadIdx.x & 31, ty = threadIdx.x >> 5;
#pragma unroll
    for (int i = 0; i < 32; i += 8)
        tile[ty + i][tx] = qkvb[(size_t)(b * SS + sx + ty + i) * 256 + 128 + dy + tx];
    __syncthreads();
#pragma unroll
    for (int i = 0; i < 32; i += 8)
        Vtg[(size_t)(b * 64 + dy + ty + i) * SS + sx + tx] = tile[tx][ty + i];
}

// ---------------------------------------------------------------------------
// bf16 MFMA GEMM, BMx128 tile (BM=128 or 64), BK=32, 256 thr = 4 waves.
// All outputs bf16. LN folding:
//   FOLD:  v = rstd*acc + bias[n] - mu*rstd*colsum[n]   (A is pre-LN trunk)
//   RESID: v += (b2f(residB[idx]) - mu)*rstd            (residual is pre-LN)
//   STATS: accumulate sum/sumsq of v into statsOut (whole-tensor LN stats)
// statsIn == nullptr -> mu=0, rstd=1 (identity, rep 0).
// Grid: blockIdx.x = M-tile (XCD affinity), blockIdx.y = N-tile.
// ---------------------------------------------------------------------------
__device__ __forceinline__ void async16(const void* g, void* l) {
    __builtin_amdgcn_global_load_lds(
        (const __attribute__((address_space(1))) void*)g,
        (__attribute__((address_space(3))) void*)l, 16, 0, 0);
}

template <bool RELU, bool RESID, bool STATS, bool FOLD, int BM>
__global__ __launch_bounds__(256) void gemm_mfma(const short* __restrict__ A,
                                                 const short* __restrict__ BT,
                                                 const float* __restrict__ bias,
                                                 const float* __restrict__ colsum,
                                                 const short* __restrict__ residB,
                                                 short* __restrict__ C,
                                                 const double* __restrict__ statsIn,
                                                 double* __restrict__ statsOut,
                                                 int M, int N, int K) {
    constexpr int NT = (BM == 128) ? 4 : 2;
    __shared__ short As[BM * 32];
    __shared__ short Bs[128 * 32];
    const int t   = threadIdx.x;
    const int wv  = t >> 6;
    const int l   = t & 63;
    const int q   = l >> 4,  l16 = l & 15;
    const int mbase = (BM == 128) ? (wv >> 1) * 64 : 0;
    const int nbase = (BM == 128) ? (wv & 1) * 64 : wv * 32;
    const long m0 = (long)blockIdx.x * BM;
    const long n0 = (long)blockIdx.y * 128;

    float muf = 0.f, rstdf = 1.f;
    if (FOLD || RESID) {
        if (statsIn) {
            double mean = statsIn[0] * (1.0 / NTOT);
            double var  = statsIn[1] * (1.0 / NTOT) - mean * mean;
            muf   = (float)mean;
            rstdf = (float)(1.0 / sqrt(var + LN_EPS));
        }
    }

    f32x4 acc[4][NT] = {};

    const int srow = wv * 16 + (l >> 2);
    const int kcol = (l & 3) * 8;

    for (int k0 = 0; k0 < K; k0 += 32) {
#pragma unroll
        for (int i = 0; i < BM / 64; ++i)
            async16(A + (m0 + srow + i * 64) * (long)K + k0 + kcol,
                    &As[(wv * 16 + i * 64) * 32 + l * 8]);
#pragma unroll
        for (int i = 0; i < 2; ++i)
            async16(BT + (n0 + srow + i * 64) * (long)K + k0 + kcol,
                    &Bs[(wv * 16 + i * 64) * 32 + l * 8]);
        __syncthreads();
        short8 af[4], bfr[NT];
#pragma unroll
        for (int i = 0; i < 4; ++i)
            af[i] = *(const short8*)&As[(mbase + i * 16 + l16) * 32 + q * 8];
#pragma unroll
        for (int i = 0; i < NT; ++i)
            bfr[i] = *(const short8*)&Bs[(nbase + i * 16 + l16) * 32 + q * 8];
#pragma unroll
        for (int mt = 0; mt < 4; ++mt)
#pragma unroll
            for (int nt = 0; nt < NT; ++nt)
                acc[mt][nt] = __builtin_amdgcn_mfma_f32_16x16x32_bf16(
                    af[mt], bfr[nt], acc[mt][nt], 0, 0, 0);
        __syncthreads();
    }

    const float mr = muf * rstdf;
    float s = 0.f, sq = 0.f;
#pragma unroll
    for (int mt = 0; mt < 4; ++mt) {
        const long rowb = m0 + mbase + mt * 16 + q * 4;
#pragma unroll
        for (int nt = 0; nt < NT; ++nt) {
            const long col = n0 + nbase + nt * 16 + l16;
            const float bv = bias[col];
            const float cs = FOLD ? colsum[col] : 0.f;
#pragma unroll
            for (int r = 0; r < 4; ++r) {
                const long idx = (rowb + r) * (long)N + col;
                float v = acc[mt][nt][r];
                if (FOLD) v = rstdf * v + bv - mr * cs;
                else      v = v + bv;
                if (RESID) v += (b2f(residB[idx]) - muf) * rstdf;
                if (RELU)  v = fmaxf(v, 0.0f);
                if (STATS) { s += v; sq += v * v; }
                C[idx] = f2b(v);
            }
        }
    }
    if (STATS) {
#pragma unroll
        for (int o = 32; o; o >>= 1) {
            s  += __shfl_down(s, o);
            sq += __shfl_down(sq, o);
        }
        float* sm = (float*)As;        // K-loop fully done; safe to reuse
        if (l == 0) { sm[wv] = s; sm[4 + wv] = sq; }
        __syncthreads();
        if (t == 0) {
            atomicAdd(&statsOut[0], (double)(sm[0] + sm[1] + sm[2] + sm[3]));
            atomicAdd(&statsOut[1], (double)(sm[4] + sm[5] + sm[6] + sm[7]));
        }
    }
}

// ---------------------------------------------------------------------------
// bf16 MFMA flash attention (unchanged from round 4/5).
// ---------------------------------------------------------------------------
__global__ __launch_bounds__(256) void attn_mfma(const short* __restrict__ qkvb,
                                                 const short* __restrict__ Vtg,
                                                 short* __restrict__ head) {
    const int b  = blockIdx.y;
    const int q0 = blockIdx.x * 64;
    const int t  = threadIdx.x;
    const int w  = t >> 6;
    const int l  = t & 63;
    const int l15 = l & 15, lq = l >> 4;
    const int l7  = l & 7,  l8 = l >> 3;

    __shared__ short Ks[64][72];
    __shared__ short Vs[64][72];
    __shared__ short Ps[4][16][68];

    short8 qf[2];
    {
        const short* qrow = qkvb + (size_t)(b * SS + q0 + w * 16 + l15) * 256;
        qf[0] = *(const short8*)(qrow + lq * 8);
        qf[1] = *(const short8*)(qrow + 32 + lq * 8);
    }

    f32x4 acc[4];
#pragma unroll
    for (int mt = 0; mt < 4; ++mt) acc[mt] = {0.f, 0.f, 0.f, 0.f};
    float m_i = -INFINITY, l_i = 0.f;
    const float sc = 0.0450712500463f;   // log2(e)/32

    short8 kreg[2], vreg[2];
    {
        const short* kb = qkvb + (size_t)(b * SS) * 256 + 64;
        kreg[0] = *(const short8*)(kb + (size_t)(w * 8 + l8) * 256 + l7 * 8);
        kreg[1] = *(const short8*)(kb + (size_t)(32 + w * 8 + l8) * 256 + l7 * 8);
        const short* vb = Vtg + (size_t)b * 64 * SS;
        vreg[0] = *(const short8*)(vb + (size_t)(w * 8 + l8) * SS + l7 * 8);
        vreg[1] = *(const short8*)(vb + (size_t)(32 + w * 8 + l8) * SS + l7 * 8);
    }

    for (int kt = 0; kt < SS / 64; ++kt) {
        __syncthreads();
        *(short8*)&Ks[w * 8 + l8][l7 * 8]      = kreg[0];
        *(short8*)&Ks[32 + w * 8 + l8][l7 * 8] = kreg[1];
        *(short8*)&Vs[w * 8 + l8][l7 * 8]      = vreg[0];
        *(short8*)&Vs[32 + w * 8 + l8][l7 * 8] = vreg[1];
        if (kt + 1 < SS / 64) {
            const short* kb = qkvb + (size_t)(b * SS + (kt + 1) * 64) * 256 + 64;
            kreg[0] = *(const short8*)(kb + (size_t)(w * 8 + l8) * 256 + l7 * 8);
            kreg[1] = *(const short8*)(kb + (size_t)(32 + w * 8 + l8) * 256 + l7 * 8);
            const short* vb = Vtg + (size_t)b * 64 * SS + (kt + 1) * 64;
            vreg[0] = *(const short8*)(vb + (size_t)(w * 8 + l8) * SS + l7 * 8);
            vreg[1] = *(const short8*)(vb + (size_t)(32 + w * 8 + l8) * SS + l7 * 8);
        }
        __syncthreads();

        f32x4 st[4];
#pragma unroll
        for (int mt = 0; mt < 4; ++mt) st[mt] = {0.f, 0.f, 0.f, 0.f};
#pragma unroll
        for (int kc = 0; kc < 2; ++kc)
#pragma unroll
            for (int mt = 0; mt < 4; ++mt) {
                short8 kf = *(const short8*)&Ks[mt * 16 + l15][kc * 32 + lq * 8];
                st[mt] = __builtin_amdgcn_mfma_f32_16x16x32_bf16(kf, qf[kc], st[mt], 0, 0, 0);
            }
        float mx = m_i;
#pragma unroll
        for (int mt = 0; mt < 4; ++mt)
#pragma unroll
            for (int r = 0; r < 4; ++r) {
                st[mt][r] *= sc;
                mx = fmaxf(mx, st[mt][r]);
            }
        mx = fmaxf(mx, __shfl_xor(mx, 16));
        mx = fmaxf(mx, __shfl_xor(mx, 32));
        float alpha = exp2f(m_i - mx);
        float rs = 0.f;
#pragma unroll
        for (int mt = 0; mt < 4; ++mt) {
            s16x4 pk;
#pragma unroll
            for (int r = 0; r < 4; ++r) {
                float p = exp2f(st[mt][r] - mx);
                rs += p;
                pk[r] = f2b(p);
            }
            *(s16x4*)&Ps[w][l15][mt * 16 + lq * 4] = pk;
        }
        rs += __shfl_xor(rs, 16);
        rs += __shfl_xor(rs, 32);
        l_i = l_i * alpha + rs;
        m_i = mx;
#pragma unroll
        for (int mt = 0; mt < 4; ++mt)
#pragma unroll
            for (int r = 0; r < 4; ++r) acc[mt][r] *= alpha;

#pragma unroll
        for (int kc = 0; kc < 2; ++kc) {
            s16x4 p0 = *(const s16x4*)&Ps[w][l15][kc * 32 + lq * 8];
            s16x4 p1 = *(const s16x4*)&Ps[w][l15][kc * 32 + lq * 8 + 4];
            short8 pf = __builtin_shufflevector(p0, p1, 0, 1, 2, 3, 4, 5, 6, 7);
#pragma unroll
            for (int mt = 0; mt < 4; ++mt) {
                short8 vf = *(const short8*)&Vs[mt * 16 + l15][kc * 32 + lq * 8];
                acc[mt] = __builtin_amdgcn_mfma_f32_16x16x32_bf16(vf, pf, acc[mt], 0, 0, 0);
            }
        }
    }
    float inv = 1.0f / l_i;
    short* out = head + (size_t)(b * SS + q0 + w * 16 + l15) * 64;
#pragma unroll
    for (int mt = 0; mt < 4; ++mt) {
        s16x4 o;
#pragma unroll
        for (int r = 0; r < 4; ++r) o[r] = f2b(acc[mt][r] * inv);
        *(s16x4*)&out[mt * 16 + lq * 4] = o;
    }
}

// ---------------------------------------------------------------------------
// Final LN2 normalize: d_out fp32 = (b2f(T1) - mu)*rstd
// ---------------------------------------------------------------------------
__global__ __launch_bounds__(256) void lnfinal_kernel(const short* __restrict__ y,
                                                      float* __restrict__ out,
                                                      const double* __restrict__ red,
                                                      int n) {
    double mean = red[0] / n;
    double var  = red[1] / n - mean * mean;
    float mu   = (float)mean;
    float rstd = (float)(1.0 / sqrt(var + LN_EPS));
    for (int i = blockIdx.x * blockDim.x + threadIdx.x; i < n;
         i += gridDim.x * blockDim.x)
        out[i] = (b2f(y[i]) - mu) * rstd;
}

// ---------------------------------------------------------------------------
extern "C" void kernel_launch(void* const* d_in, const int* in_sizes, int n_in,
                              void* d_out, int out_size, void* d_ws, size_t ws_size,
                              hipStream_t stream) {
    const int*   ids = (const int*)d_in[0];
    const float* emb = (const float*)d_in[1];
    const float* Wq  = (const float*)d_in[2];
    const float* bq  = (const float*)d_in[3];
    const float* Wk  = (const float*)d_in[4];
    const float* bk  = (const float*)d_in[5];
    const float* Wv  = (const float*)d_in[6];
    const float* bv  = (const float*)d_in[7];
    const float* Wo  = (const float*)d_in[8];
    const float* bo  = (const float*)d_in[9];
    const float* W1  = (const float*)d_in[10];
    const float* b1  = (const float*)d_in[11];
    const float* W2  = (const float*)d_in[12];
    const float* b2  = (const float*)d_in[13];

    float* xout = (float*)d_out;                     // final output only
    char* w = (char*)d_ws;

    // Buffers (bf16 unless noted):
    //   hch  [16384][2048] (full) or [8192][2048] (chunked) -- FF hidden
    //   qkvb [16384][256], Vtg [8][64][2048], head [16384][64]  (alias in hch)
    //   T1   trunk y (rep input / FF2 output), T2 trunk z (outproj output)
    const bool big = ws_size >= (size_t)105195712 + 256;

    short *qkvb, *Vtg, *head, *T1, *T2, *hch, *WqkvT, *WoST, *W1T, *W2T;
    float *bqkv, *csq, *csw1; double* red;

    if (big) {
        hch   = (short*)(w + 0);                     // 64 MB
        qkvb  = (short*)(w + 0);                     //  8 MB (alias)
        Vtg   = (short*)(w + 8388608);               //  2 MB (alias)
        head  = (short*)(w + 10485760);              //  2 MB (alias)
        T1    = (short*)(w + 67108864);              // 16 MB
        T2    = (short*)(w + 83886080);              // 16 MB
        WqkvT = (short*)(w + 100663296);
        bqkv  = (float*)(w + 100925440);
        csq   = (float*)(w + 100926464);
        WoST  = (short*)(w + 100927488);
        W1T   = (short*)(w + 100993024);
        csw1  = (float*)(w + 103090176);
        W2T   = (short*)(w + 103098368);
        red   = (double*)(w + 105195520);
    } else {
        hch   = (short*)(w + 0);                     // 32 MB (M=8192 chunks)
        qkvb  = (short*)(w + 0);
        Vtg   = (short*)(w + 8388608);
        head  = (short*)(w + 10485760);
        T1    = (short*)(w + 33554432);
        T2    = (short*)(w + 50331648);
        WqkvT = (short*)(w + 67108864);
        bqkv  = (float*)(w + 67371008);
        csq   = (float*)(w + 67372032);
        WoST  = (short*)(w + 67373056);
        W1T   = (short*)(w + 67438592);
        csw1  = (float*)(w + 69535744);
        W2T   = (short*)(w + 69543936);
        red   = (double*)(w + 71641088);
    }

    // ---- setup (once per launch) ----
    packqkvT_kernel<<<(256 * 512 + 255) / 256, 256, 0, stream>>>(Wq, Wk, Wv, bq, bk, bv, WqkvT, bqkv);
    wosumT_kernel<<<(512 * 64 + 255) / 256, 256, 0, stream>>>(Wo, WoST);
    transpose_b16<<<dim3(2048 / 32, 512 / 32), 256, 0, stream>>>(W1, W1T, 512, 2048);
    transpose_b16<<<dim3(512 / 32, 2048 / 32), 256, 0, stream>>>(W2, W2T, 2048, 512);
    colsum_kernel<<<9, 256, 0, stream>>>(WqkvT, W1T, csq, csw1);
    embed_kernel<<<NTOT / 256, 256, 0, stream>>>(ids, emb, T1, red);

    for (int rep = 0; rep < 6; ++rep) {
        const double* sprev = rep ? red + 4 * (rep - 1) + 2 : nullptr;  // LN2 stats of prev rep
        double* red1 = red + 4 * rep;        // LN1 stats (over z = outproj out)
        double* red2 = red + 4 * rep + 2;    // LN2 stats (over y' = FF2 out)

        // QKV: LN2-folded  qkvb = LN(T1) @ Wqkv + bqkv   [16384][256]
        gemm_mfma<false, false, false, true, 64><<<dim3(256, 2), 256, 0, stream>>>(
            T1, WqkvT, bqkv, csq, nullptr, qkvb, sprev, nullptr, ROWS, 256, DM);
        // V transpose
        vtrans_kernel<<<dim3(SS / 32, 2, BB), 256, 0, stream>>>(qkvb, Vtg);
        // flash attention -> head
        attn_mfma<<<dim3(SS / 64, BB), 256, 0, stream>>>(qkvb, Vtg, head);
        // out-proj: T2 = head @ WoS + bo + LN(T1); stats -> red1
        gemm_mfma<false, true, true, false, 64><<<dim3(256, 4), 256, 0, stream>>>(
            head, WoST, bo, nullptr, T1, T2, sprev, red1, ROWS, DM, DK);
        // FF (LN1 folded into FF1; resid LN1(T2) in FF2; stats -> red2)
        if (big) {
            gemm_mfma<true, false, false, true, 128><<<dim3(128, 16), 256, 0, stream>>>(
                T2, W1T, b1, csw1, nullptr, hch, red1, nullptr, ROWS, DFF, DM);
            gemm_mfma<false, true, true, false, 64><<<dim3(256, 4), 256, 0, stream>>>(
                hch, W2T, b2, nullptr, T2, T1, red1, red2, ROWS, DM, DFF);
        } else {
            for (int c = 0; c < 2; ++c) {
                const size_t off = (size_t)c * 8192 * DM;
                gemm_mfma<true, false, false, true, 128><<<dim3(64, 16), 256, 0, stream>>>(
                    T2 + off, W1T, b1, csw1, nullptr, hch, red1, nullptr, 8192, DFF, DM);
                gemm_mfma<false, true, true, false, 64><<<dim3(128, 4), 256, 0, stream>>>(
                    hch, W2T, b2, nullptr, T2 + off, T1 + off, red1, red2, 8192, DM, DFF);
            }
        }
    }
    // final LN2 normalize -> fp32 output
    lnfinal_kernel<<<4096, 256, 0, stream>>>(T1, xout, red + 4 * 5 + 2, NTOT);
}